// Round 1
// baseline (972.593 us; speedup 1.0000x reference)
//
#include <hip/hip_runtime.h>
#include <math.h>

#define NUSER 60000
#define NITEM 60000
#define NNODE 120000

__device__ __forceinline__ float leaky02(float x) { return x > 0.f ? x : 0.2f * x; }

__device__ __forceinline__ float inv_ord(unsigned int u) {
  unsigned int bits = (u & 0x80000000u) ? (u & 0x7FFFFFFFu) : ~u;
  return __uint_as_float(bits);
}
__device__ __forceinline__ unsigned int ord_of(float f) {
  unsigned int u = __float_as_uint(f);
  return (u & 0x80000000u) ? ~u : (u | 0x80000000u);
}

// ---- fused weights: Wf[r][n] = sum_j Wa[r][j] * Wg[j][n];  bf[n] = sum_j ba[j] * Wg[j][n]
__global__ void fusew_kernel(const float* __restrict__ Wa, const float* __restrict__ ba,
                             const float* __restrict__ Wg, float* __restrict__ Wf,
                             float* __restrict__ bf, int K) {
  int n = threadIdx.x;   // 0..127
  int r = blockIdx.x;    // 0..K (K+1 blocks; last row does bias)
  if (r < K) {
    float acc = 0.f;
#pragma unroll 8
    for (int j = 0; j < 128; ++j) acc = fmaf(Wa[r * 128 + j], Wg[j * 128 + n], acc);
    Wf[r * 128 + n] = acc;
  } else {
    float acc = 0.f;
    for (int j = 0; j < 128; ++j) acc = fmaf(ba[j], Wg[j * 128 + n], acc);
    bf[n] = acc;
  }
}

// ---- row-tiled GEMM: C[M][NC] = A[M][K] @ W[K][NC] + bias.  blockDim=(NC,TY), 16 rows/block.
template <int NC, int TY, int RPT>
__global__ __launch_bounds__(256) void gemm_rt(const float* __restrict__ A,
                                               const float* __restrict__ W,
                                               const float* __restrict__ bias,
                                               float* __restrict__ C, int K) {
  const int n = threadIdx.x;
  const int m0 = blockIdx.x * (TY * RPT) + threadIdx.y * RPT;
  float acc[RPT];
  float b = bias[n];
#pragma unroll
  for (int r = 0; r < RPT; ++r) acc[r] = b;
  const float* a0 = A + (size_t)m0 * K;
  for (int k = 0; k < K; k += 4) {
    float w0 = W[(k + 0) * NC + n];
    float w1 = W[(k + 1) * NC + n];
    float w2 = W[(k + 2) * NC + n];
    float w3 = W[(k + 3) * NC + n];
#pragma unroll
    for (int r = 0; r < RPT; ++r) {
      float4 a = *reinterpret_cast<const float4*>(a0 + (size_t)r * K + k);
      acc[r] = fmaf(a.x, w0, acc[r]);
      acc[r] = fmaf(a.y, w1, acc[r]);
      acc[r] = fmaf(a.z, w2, acc[r]);
      acc[r] = fmaf(a.w, w3, acc[r]);
    }
  }
#pragma unroll
  for (int r = 0; r < RPT; ++r) C[(size_t)(m0 + r) * NC + n] = acc[r];
}

// ---- el/er: per-row dots with attn_l/attn_r. One wave per row.
__global__ __launch_bounds__(256) void elr_kernel(const float* __restrict__ z,
                                                  const float* __restrict__ al,
                                                  const float* __restrict__ ar,
                                                  float* __restrict__ el, float* __restrict__ er) {
  int row = blockIdx.x * 4 + (threadIdx.x >> 6);
  int lane = threadIdx.x & 63;
  const float* zr = z + (size_t)row * 128;
  float z0 = zr[lane], z1 = zr[lane + 64];
  float sl = z0 * al[lane] + z1 * al[lane + 64];
  float sr = z0 * ar[lane] + z1 * ar[lane + 64];
#pragma unroll
  for (int m = 32; m; m >>= 1) {
    sl += __shfl_xor(sl, m, 64);
    sr += __shfl_xor(sr, m, 64);
  }
  if (lane == 0) { el[row] = sl; er[row] = sr; }
}

// ---- degree histogram
__global__ void hist_kernel(const int* __restrict__ dst, int* __restrict__ deg, int E) {
  int i = blockIdx.x * blockDim.x + threadIdx.x;
  if (i < E) atomicAdd(&deg[dst[i]], 1);
}

// ---- 3-kernel exclusive scan -> offsets[N+1]
__global__ void scan1_kernel(const int* __restrict__ deg, int* __restrict__ offs,
                             int* __restrict__ bsum, int N) {
  __shared__ int s[256];
  int t = threadIdx.x;
  int i = blockIdx.x * 256 + t;
  int v = (i < N) ? deg[i] : 0;
  s[t] = v;
  __syncthreads();
  for (int off = 1; off < 256; off <<= 1) {
    int add = (t >= off) ? s[t - off] : 0;
    __syncthreads();
    s[t] += add;
    __syncthreads();
  }
  if (i < N) offs[i + 1] = s[t];
  if (t == 255) bsum[blockIdx.x] = s[255];
  if (i == 0) offs[0] = 0;
}
__global__ void scan2_kernel(int* __restrict__ bsum, int NB) {
  __shared__ int s[512];
  int t = threadIdx.x;
  s[t] = (t < NB) ? bsum[t] : 0;
  __syncthreads();
  for (int off = 1; off < 512; off <<= 1) {
    int add = (t >= off) ? s[t - off] : 0;
    __syncthreads();
    s[t] += add;
    __syncthreads();
  }
  if (t < NB) bsum[t] = s[t];
}
__global__ void scan3_kernel(int* __restrict__ offs, const int* __restrict__ bsum, int N) {
  int b = blockIdx.x;
  int i = b * 256 + threadIdx.x;
  if (b > 0 && i < N) offs[i + 1] += bsum[b - 1];
}

// ---- scatter edges into dst-sorted order (store src only)
__global__ void scatter_kernel(const int* __restrict__ src, const int* __restrict__ dst,
                               const int* __restrict__ offs, int* __restrict__ cursor,
                               int* __restrict__ ssrc, int E) {
  int i = blockIdx.x * blockDim.x + threadIdx.x;
  if (i < E) {
    int d = dst[i];
    int p = atomicAdd(&cursor[d], 1);
    ssrc[offs[d] + p] = src[i];
  }
}

// ---- GAT aggregation: one wave per dst node.
__global__ __launch_bounds__(256) void aggregate_kernel(
    const float* __restrict__ z, const float* __restrict__ el, const float* __restrict__ er,
    const int* __restrict__ offs, const int* __restrict__ ssrc,
    const float* __restrict__ gat_bias, float* __restrict__ h) {
  int d = blockIdx.x * 4 + (threadIdx.x >> 6);
  int lane = threadIdx.x & 63;
  int s0 = offs[d], s1 = offs[d + 1];
  float erd = er[d];
  // pass 1: segment max (strided over lanes, then reduce)
  float m = -1e30f;
  for (int i = s0 + lane; i < s1; i += 64) {
    float e = leaky02(el[ssrc[i]] + erd);
    m = fmaxf(m, e);
  }
#pragma unroll
  for (int mm = 32; mm; mm >>= 1) m = fmaxf(m, __shfl_xor(m, mm, 64));
  // pass 2: exp weights + weighted row accumulation
  float acc0 = 0.f, acc1 = 0.f, ssum = 0.f;
  for (int i = s0; i < s1; ++i) {
    int s = ssrc[i];
    float w = __expf(leaky02(el[s] + erd) - m);
    ssum += w;
    const float* zr = z + (size_t)s * 128;
    acc0 += w * zr[lane];
    acc1 += w * zr[lane + 64];
  }
  float inv = 1.f / ssum;
  float o0 = acc0 * inv + gat_bias[lane];
  float o1 = acc1 * inv + gat_bias[lane + 64];
  o0 = (o0 > 0.f) ? o0 : (__expf(o0) - 1.f);
  o1 = (o1 > 0.f) ? o1 : (__expf(o1) - 1.f);
  h[(size_t)d * 128 + lane] = o0;
  h[(size_t)d * 128 + lane + 64] = o1;
}

// ---- link scores -> log_sigmoid, store l, track max (ordered-uint atomicMax)
__global__ __launch_bounds__(256) void score_kernel(const float* __restrict__ h,
                                                    const int* __restrict__ sa,
                                                    const int* __restrict__ sb,
                                                    float* __restrict__ lout,
                                                    unsigned int* __restrict__ maxacc, int P) {
  __shared__ float wmax[4];
  int lane = threadIdx.x & 63, wv = threadIdx.x >> 6;
  float lmax = -1e30f;
  for (int i = blockIdx.x * 4 + wv; i < P; i += gridDim.x * 4) {
    int a = sa[i], b = sb[i];
    const float* ha = h + (size_t)a * 128;
    const float* hb = h + (size_t)b * 128;
    float s = ha[lane] * hb[lane] + ha[lane + 64] * hb[lane + 64];
#pragma unroll
    for (int mm = 32; mm; mm >>= 1) s += __shfl_xor(s, mm, 64);
    float l = fminf(s, 0.f) - log1pf(__expf(-fabsf(s)));
    if (lane == 0) lout[i] = l;
    lmax = fmaxf(lmax, l);
  }
  if (lane == 0) wmax[wv] = lmax;
  __syncthreads();
  if (threadIdx.x == 0) {
    float bm = fmaxf(fmaxf(wmax[0], wmax[1]), fmaxf(wmax[2], wmax[3]));
    atomicMax(maxacc, ord_of(bm));
  }
}

// ---- thresholded sum: sum of l where !(l > hold), hold = k_T * max(l)
__global__ __launch_bounds__(256) void loss_sum_kernel(const float* __restrict__ l,
                                                       const unsigned int* __restrict__ maxacc,
                                                       const int* __restrict__ alpha, int which,
                                                       float* __restrict__ sums, int P) {
  __shared__ float sdata[256];
  float a = (float)alpha[0];
  float kT = (0.5f <= a) ? 0.5f : a;
  float hold = kT * inv_ord(maxacc[which]);
  float s = 0.f;
  for (int i = blockIdx.x * 256 + threadIdx.x; i < P; i += gridDim.x * 256) {
    float v = l[i];
    if (!(v > hold)) s += v;
  }
  sdata[threadIdx.x] = s;
  __syncthreads();
  for (int off = 128; off; off >>= 1) {
    if (threadIdx.x < off) sdata[threadIdx.x] += sdata[threadIdx.x + off];
    __syncthreads();
  }
  if (threadIdx.x == 0) atomicAdd(&sums[which], sdata[0]);
}

__global__ void final_kernel(const float* __restrict__ sums, float* __restrict__ out) {
  out[0] = -(sums[0] + sums[1]);
}

extern "C" void kernel_launch(void* const* d_in, const int* in_sizes, int n_in,
                              void* d_out, int out_size, void* d_ws, size_t ws_size,
                              hipStream_t stream) {
  const float* feat_user = (const float*)d_in[0];
  const float* feat_item = (const float*)d_in[1];
  const float* W_user = (const float*)d_in[2];
  const float* b_user = (const float*)d_in[3];
  const float* W_item = (const float*)d_in[4];
  const float* b_item = (const float*)d_in[5];
  const float* W_gat = (const float*)d_in[6];
  const float* attn_l = (const float*)d_in[7];
  const float* attn_r = (const float*)d_in[8];
  const float* gat_bias = (const float*)d_in[9];
  const float* W_pred = (const float*)d_in[10];
  const float* b_pred = (const float*)d_in[11];
  const int* src = (const int*)d_in[12];
  const int* dst = (const int*)d_in[13];
  const int* pos_src = (const int*)d_in[14];
  const int* pos_dst = (const int*)d_in[15];
  const int* neg_src = (const int*)d_in[16];
  const int* neg_dst = (const int*)d_in[17];
  const int* alpha = (const int*)d_in[18];
  const int E = in_sizes[12];
  const int P = in_sizes[14];

  // ---- workspace layout
  char* p = (char*)d_ws;
  auto alloc = [&](size_t bytes) {
    char* r = p;
    p += (bytes + 255) & ~(size_t)255;
    return r;
  };
  float* z = (float*)alloc((size_t)NNODE * 128 * 4);
  float* h = (float*)alloc((size_t)NNODE * 128 * 4);
  float* el = (float*)alloc((size_t)NNODE * 4);
  float* er = (float*)alloc((size_t)NNODE * 4);
  float* Wf_u = (float*)alloc(256 * 128 * 4);
  float* bf_u = (float*)alloc(128 * 4);
  float* Wf_i = (float*)alloc(128 * 128 * 4);
  float* bf_i = (float*)alloc(128 * 4);
  int* offs = (int*)alloc((size_t)(NNODE + 4) * 4);
  int* ssrc = (int*)alloc((size_t)E * 4);
  float* l_pos = (float*)alloc((size_t)P * 4);
  float* l_neg = (float*)alloc((size_t)P * 4);
  int* bsum = (int*)alloc(512 * 4);
  // zero region (one memset): deg | cursor | maxacc[2] | sums[2]
  int* deg = (int*)alloc((size_t)(2 * NNODE + 8) * 4);
  int* cursor = deg + NNODE;
  unsigned int* maxacc = (unsigned int*)(cursor + NNODE);
  float* sums = (float*)(maxacc + 2);

  float* out_loss = (float*)d_out;
  float* out_pred = out_loss + 1;

  hipMemsetAsync(deg, 0, (size_t)(2 * NNODE + 8) * 4, stream);

  // weight fusion: Wf = W_type @ W_gat (+ bias pushed through)
  fusew_kernel<<<257, 128, 0, stream>>>(W_user, b_user, W_gat, Wf_u, bf_u, 256);
  fusew_kernel<<<129, 128, 0, stream>>>(W_item, b_item, W_gat, Wf_i, bf_i, 128);

  // z = feat @ Wf + bf  (user rows then item rows)
  gemm_rt<128, 2, 8><<<dim3(NUSER / 16), dim3(128, 2), 0, stream>>>(feat_user, Wf_u, bf_u, z, 256);
  gemm_rt<128, 2, 8><<<dim3(NITEM / 16), dim3(128, 2), 0, stream>>>(feat_item, Wf_i, bf_i,
                                                                    z + (size_t)NUSER * 128, 128);
  // attention logits per node
  elr_kernel<<<NNODE / 4, 256, 0, stream>>>(z, attn_l, attn_r, el, er);

  // CSR by dst
  int egrid = (E + 255) / 256;
  hist_kernel<<<egrid, 256, 0, stream>>>(dst, deg, E);
  int ngrid = (NNODE + 255) / 256;  // 469
  scan1_kernel<<<ngrid, 256, 0, stream>>>(deg, offs, bsum, NNODE);
  scan2_kernel<<<1, 512, 0, stream>>>(bsum, ngrid);
  scan3_kernel<<<ngrid, 256, 0, stream>>>(offs, bsum, NNODE);
  scatter_kernel<<<egrid, 256, 0, stream>>>(src, dst, offs, cursor, ssrc, E);

  // GAT edge-softmax aggregation -> h
  aggregate_kernel<<<NNODE / 4, 256, 0, stream>>>(z, el, er, offs, ssrc, gat_bias, h);

  // link scores + loss
  score_kernel<<<1024, 256, 0, stream>>>(h, pos_src, pos_dst, l_pos, maxacc + 0, P);
  score_kernel<<<1024, 256, 0, stream>>>(h, neg_src, neg_dst, l_neg, maxacc + 1, P);
  loss_sum_kernel<<<512, 256, 0, stream>>>(l_pos, maxacc, alpha, 0, sums, P);
  loss_sum_kernel<<<512, 256, 0, stream>>>(l_neg, maxacc, alpha, 1, sums, P);
  final_kernel<<<1, 1, 0, stream>>>(sums, out_loss);

  // prediction head: out = h[:NUSER] @ W_pred + b_pred
  gemm_rt<64, 4, 4><<<dim3(NUSER / 16), dim3(64, 4), 0, stream>>>(h, W_pred, b_pred, out_pred, 128);

  (void)n_in; (void)out_size; (void)ws_size;
}

// Round 2
// 519.182 us; speedup vs baseline: 1.8733x; 1.8733x over previous
//
#include <hip/hip_runtime.h>
#include <hip/hip_bf16.h>
#include <math.h>

#define NUSER 60000
#define NITEM 60000
#define NNODE 120000

typedef __attribute__((ext_vector_type(8))) short bf16x8;
typedef __attribute__((ext_vector_type(4))) float f32x4;
typedef __attribute__((ext_vector_type(8))) unsigned short u16x8;

__device__ __forceinline__ float leaky02(float x) { return x > 0.f ? x : 0.2f * x; }

__device__ __forceinline__ float inv_ord(unsigned int u) {
  unsigned int bits = (u & 0x80000000u) ? (u & 0x7FFFFFFFu) : ~u;
  return __uint_as_float(bits);
}
__device__ __forceinline__ unsigned int ord_of(float f) {
  unsigned int u = __float_as_uint(f);
  return (u & 0x80000000u) ? ~u : (u | 0x80000000u);
}
__device__ __forceinline__ short f2bs(float f) {
  __hip_bfloat16 h = __float2bfloat16(f);
  return *reinterpret_cast<short*>(&h);
}
__device__ __forceinline__ float bf2f(unsigned short u) {
  union { unsigned int u32; float f; } x;
  x.u32 = ((unsigned int)u) << 16;
  return x.f;
}

// ---- fused weights: Wf[r][n] = sum_j Wa[r][j] * Wg[j][n];  bf[n] = sum_j ba[j] * Wg[j][n]
__global__ void fusew_kernel(const float* __restrict__ Wa, const float* __restrict__ ba,
                             const float* __restrict__ Wg, float* __restrict__ Wf,
                             float* __restrict__ bf, int K) {
  int n = threadIdx.x;   // 0..127
  int r = blockIdx.x;    // 0..K (K+1 blocks; last row does bias)
  if (r < K) {
    float acc = 0.f;
#pragma unroll 8
    for (int j = 0; j < 128; ++j) acc = fmaf(Wa[r * 128 + j], Wg[j * 128 + n], acc);
    Wf[r * 128 + n] = acc;
  } else {
    float acc = 0.f;
    for (int j = 0; j < 128; ++j) acc = fmaf(ba[j], Wg[j * 128 + n], acc);
    bf[n] = acc;
  }
}

// ---- pack W (fp32 [K][N]) into MFMA B-fragment layout, bf16.
// Bp flat idx t = ((ks*NT + nt)*64 + lane)*8 + j  ->  W[ks*32 + (lane>>4)*8 + j][nt*16 + (lane&15)]
__global__ void packb_kernel(const float* __restrict__ W, __hip_bfloat16* __restrict__ Bp,
                             int K, int N) {
  int t = blockIdx.x * 256 + threadIdx.x;
  if (t >= K * N) return;
  int j = t & 7;
  int lane = (t >> 3) & 63;
  int rest = t >> 9;
  int NT = N >> 4;
  int nt = rest % NT;
  int ks = rest / NT;
  int k = ks * 32 + ((lane >> 4) << 3) + j;
  int n = nt * 16 + (lane & 15);
  Bp[t] = __float2bfloat16(W[k * N + n]);
}

// ---- z GEMM: z[M][128] (bf16) = A[M][K] (fp32, cvt inline) @ Bp (packed bf16) + bias.
// Also computes el/er (fused epilogue via LDS transpose). 4 waves x 16 rows = 64 rows/block.
template <int K>
__global__ __launch_bounds__(256) void zgemm_kernel(
    const float* __restrict__ A, const __hip_bfloat16* __restrict__ Bp,
    const float* __restrict__ bias, const float* __restrict__ al, const float* __restrict__ ar,
    __hip_bfloat16* __restrict__ z, float* __restrict__ el, float* __restrict__ er, int M) {
  __shared__ float lds[64][140];
  const int lane = threadIdx.x & 63, wv = threadIdx.x >> 6;
  const int m0 = blockIdx.x * 64 + wv * 16;
  int arow = m0 + (lane & 15);
  if (arow >= M) arow = M - 1;
  const float* a0 = A + (size_t)arow * K + ((lane >> 4) << 3);
  const bf16x8* bp = (const bf16x8*)Bp;
  f32x4 acc[8] = {};
#pragma unroll
  for (int ks = 0; ks < K / 32; ++ks) {
    float4 a1 = *(const float4*)(a0 + ks * 32);
    float4 a2 = *(const float4*)(a0 + ks * 32 + 4);
    bf16x8 af;
    af[0] = f2bs(a1.x); af[1] = f2bs(a1.y); af[2] = f2bs(a1.z); af[3] = f2bs(a1.w);
    af[4] = f2bs(a2.x); af[5] = f2bs(a2.y); af[6] = f2bs(a2.z); af[7] = f2bs(a2.w);
#pragma unroll
    for (int nt = 0; nt < 8; ++nt) {
      bf16x8 bfr = bp[(ks * 8 + nt) * 64 + lane];
      acc[nt] = __builtin_amdgcn_mfma_f32_16x16x32_bf16(af, bfr, acc[nt], 0, 0, 0);
    }
  }
  // C layout (m89): row = (lane>>4)*4 + r, col = lane&15 (within 16x16 tile)
#pragma unroll
  for (int nt = 0; nt < 8; ++nt) {
    float b = bias[nt * 16 + (lane & 15)];
#pragma unroll
    for (int r = 0; r < 4; ++r)
      lds[wv * 16 + (lane >> 4) * 4 + r][nt * 16 + (lane & 15)] = acc[nt][r] + b;
  }
  __syncthreads();
  // phase 2: row-major readout -> bf16 z + fused el/er
  int row = threadIdx.x >> 2;  // 0..63
  int q = threadIdx.x & 3;     // 32-col chunk
  int gm = blockIdx.x * 64 + row;
  float pl = 0.f, pr = 0.f;
  if (gm < M) {
    const float* lrow = &lds[row][q * 32];
#pragma unroll
    for (int v4 = 0; v4 < 4; ++v4) {
      u16x8 outv;
#pragma unroll
      for (int j = 0; j < 8; ++j) {
        float f = lrow[v4 * 8 + j];
        int c = q * 32 + v4 * 8 + j;
        pl = fmaf(f, al[c], pl);
        pr = fmaf(f, ar[c], pr);
        outv[j] = (unsigned short)f2bs(f);
      }
      *(u16x8*)((unsigned short*)z + (size_t)gm * 128 + q * 32 + v4 * 8) = outv;
    }
  }
  pl += __shfl_xor(pl, 1, 64); pl += __shfl_xor(pl, 2, 64);
  pr += __shfl_xor(pr, 1, 64); pr += __shfl_xor(pr, 2, 64);
  if (q == 0 && gm < M) { el[gm] = pl; er[gm] = pr; }
}

// ---- pred GEMM: out[M][64] (fp32) = h[M][128] (bf16) @ Bp(W_pred packed) + b_pred
__global__ __launch_bounds__(256) void predgemm_kernel(
    const __hip_bfloat16* __restrict__ h, const __hip_bfloat16* __restrict__ Bp,
    const float* __restrict__ bias, float* __restrict__ out, int M) {
  const int lane = threadIdx.x & 63, wv = threadIdx.x >> 6;
  const int m0 = blockIdx.x * 64 + wv * 16;
  int arow = m0 + (lane & 15);
  if (arow >= M) arow = M - 1;
  const bf16x8* a0 = (const bf16x8*)(h + (size_t)arow * 128) + (lane >> 4);
  const bf16x8* bp = (const bf16x8*)Bp;
  f32x4 acc[4] = {};
#pragma unroll
  for (int ks = 0; ks < 4; ++ks) {
    bf16x8 af = a0[ks * 4];
#pragma unroll
    for (int nt = 0; nt < 4; ++nt) {
      bf16x8 bfr = bp[(ks * 4 + nt) * 64 + lane];
      acc[nt] = __builtin_amdgcn_mfma_f32_16x16x32_bf16(af, bfr, acc[nt], 0, 0, 0);
    }
  }
#pragma unroll
  for (int nt = 0; nt < 4; ++nt) {
    int col = nt * 16 + (lane & 15);
    float b = bias[col];
#pragma unroll
    for (int r = 0; r < 4; ++r) {
      int m = m0 + (lane >> 4) * 4 + r;
      if (m < M) out[(size_t)m * 64 + col] = acc[nt][r] + b;
    }
  }
}

// ---- degree histogram
__global__ void hist_kernel(const int* __restrict__ dst, int* __restrict__ deg, int E) {
  int i = blockIdx.x * blockDim.x + threadIdx.x;
  if (i < E) atomicAdd(&deg[dst[i]], 1);
}

// ---- 3-kernel exclusive scan -> offsets[N+1]
__global__ void scan1_kernel(const int* __restrict__ deg, int* __restrict__ offs,
                             int* __restrict__ bsum, int N) {
  __shared__ int s[256];
  int t = threadIdx.x;
  int i = blockIdx.x * 256 + t;
  int v = (i < N) ? deg[i] : 0;
  s[t] = v;
  __syncthreads();
  for (int off = 1; off < 256; off <<= 1) {
    int add = (t >= off) ? s[t - off] : 0;
    __syncthreads();
    s[t] += add;
    __syncthreads();
  }
  if (i < N) offs[i + 1] = s[t];
  if (t == 255) bsum[blockIdx.x] = s[255];
  if (i == 0) offs[0] = 0;
}
__global__ void scan2_kernel(int* __restrict__ bsum, int NB) {
  __shared__ int s[512];
  int t = threadIdx.x;
  s[t] = (t < NB) ? bsum[t] : 0;
  __syncthreads();
  for (int off = 1; off < 512; off <<= 1) {
    int add = (t >= off) ? s[t - off] : 0;
    __syncthreads();
    s[t] += add;
    __syncthreads();
  }
  if (t < NB) bsum[t] = s[t];
}
__global__ void scan3_kernel(int* __restrict__ offs, const int* __restrict__ bsum, int N) {
  int b = blockIdx.x;
  int i = b * 256 + threadIdx.x;
  if (b > 0 && i < N) offs[i + 1] += bsum[b - 1];
}

// ---- scatter edges into dst-sorted order (store src only)
__global__ void scatter_kernel(const int* __restrict__ src, const int* __restrict__ dst,
                               const int* __restrict__ offs, int* __restrict__ cursor,
                               int* __restrict__ ssrc, int E) {
  int i = blockIdx.x * blockDim.x + threadIdx.x;
  if (i < E) {
    int d = dst[i];
    int p = atomicAdd(&cursor[d], 1);
    ssrc[offs[d] + p] = src[i];
  }
}

// ---- GAT aggregation: one wave per dst node. z/h in bf16.
__global__ __launch_bounds__(256) void aggregate_kernel(
    const __hip_bfloat16* __restrict__ z, const float* __restrict__ el,
    const float* __restrict__ er, const int* __restrict__ offs, const int* __restrict__ ssrc,
    const float* __restrict__ gat_bias, __hip_bfloat16* __restrict__ h) {
  int d = blockIdx.x * 4 + (threadIdx.x >> 6);
  int lane = threadIdx.x & 63;
  int s0 = offs[d], s1 = offs[d + 1];
  int deg = s1 - s0;
  float erd = er[d];
  // per-lane edge logits kept in registers (up to 128 edges)
  float e0 = -1e30f, e1 = -1e30f;
  int src0 = 0, src1 = 0;
  if (lane < deg) { src0 = ssrc[s0 + lane]; e0 = leaky02(el[src0] + erd); }
  if (64 + lane < deg) { src1 = ssrc[s0 + 64 + lane]; e1 = leaky02(el[src1] + erd); }
  float m = fmaxf(e0, e1);
  for (int i = s0 + 128 + lane; i < s1; i += 64) {  // rare deep tail
    m = fmaxf(m, leaky02(el[ssrc[i]] + erd));
  }
#pragma unroll
  for (int mm = 32; mm; mm >>= 1) m = fmaxf(m, __shfl_xor(m, mm, 64));

  float acc0 = 0.f, acc1 = 0.f, ssum = 0.f;
  const unsigned short* zb = (const unsigned short*)z;
  if (deg <= 128) {
    int sN = __shfl(src0, 0, 64);
    ushort2 zv = *(const ushort2*)(zb + (size_t)sN * 128 + lane * 2);
    for (int i = 0; i < deg; ++i) {
      ushort2 cur = zv;
      if (i + 1 < deg) {
        int nn = i + 1;
        int sn = (nn < 64) ? __shfl(src0, nn, 64) : __shfl(src1, nn - 64, 64);
        zv = *(const ushort2*)(zb + (size_t)sn * 128 + lane * 2);
      }
      float ei = (i < 64) ? __shfl(e0, i, 64) : __shfl(e1, i - 64, 64);
      float w = __expf(ei - m);
      ssum += w;
      acc0 = fmaf(w, bf2f(cur.x), acc0);
      acc1 = fmaf(w, bf2f(cur.y), acc1);
    }
  } else {
    for (int i = s0; i < s1; ++i) {
      int s = ssrc[i];
      float w = __expf(leaky02(el[s] + erd) - m);
      ssum += w;
      ushort2 cur = *(const ushort2*)(zb + (size_t)s * 128 + lane * 2);
      acc0 = fmaf(w, bf2f(cur.x), acc0);
      acc1 = fmaf(w, bf2f(cur.y), acc1);
    }
  }
  float inv = 1.f / ssum;
  float o0 = acc0 * inv + gat_bias[lane * 2];
  float o1 = acc1 * inv + gat_bias[lane * 2 + 1];
  o0 = (o0 > 0.f) ? o0 : (__expf(o0) - 1.f);
  o1 = (o1 > 0.f) ? o1 : (__expf(o1) - 1.f);
  ushort2 ov;
  ov.x = (unsigned short)f2bs(o0);
  ov.y = (unsigned short)f2bs(o1);
  *(ushort2*)((unsigned short*)h + (size_t)d * 128 + lane * 2) = ov;
}

// ---- link scores -> log_sigmoid, store l, track max (ordered-uint atomicMax)
__global__ __launch_bounds__(256) void score_kernel(const __hip_bfloat16* __restrict__ h,
                                                    const int* __restrict__ sa,
                                                    const int* __restrict__ sb,
                                                    float* __restrict__ lout,
                                                    unsigned int* __restrict__ maxacc, int P) {
  __shared__ float wmax[4];
  int lane = threadIdx.x & 63, wv = threadIdx.x >> 6;
  const unsigned short* hb16 = (const unsigned short*)h;
  float lmax = -1e30f;
  for (int i = blockIdx.x * 4 + wv; i < P; i += gridDim.x * 4) {
    int a = sa[i], b = sb[i];
    ushort2 va = *(const ushort2*)(hb16 + (size_t)a * 128 + lane * 2);
    ushort2 vb = *(const ushort2*)(hb16 + (size_t)b * 128 + lane * 2);
    float s = bf2f(va.x) * bf2f(vb.x) + bf2f(va.y) * bf2f(vb.y);
#pragma unroll
    for (int mm = 32; mm; mm >>= 1) s += __shfl_xor(s, mm, 64);
    float l = fminf(s, 0.f) - log1pf(__expf(-fabsf(s)));
    if (lane == 0) lout[i] = l;
    lmax = fmaxf(lmax, l);
  }
  if (lane == 0) wmax[wv] = lmax;
  __syncthreads();
  if (threadIdx.x == 0) {
    float bm = fmaxf(fmaxf(wmax[0], wmax[1]), fmaxf(wmax[2], wmax[3]));
    atomicMax(maxacc, ord_of(bm));
  }
}

// ---- thresholded sum: sum of l where !(l > hold), hold = k_T * max(l)
__global__ __launch_bounds__(256) void loss_sum_kernel(const float* __restrict__ l,
                                                       const unsigned int* __restrict__ maxacc,
                                                       const int* __restrict__ alpha, int which,
                                                       float* __restrict__ sums, int P) {
  __shared__ float sdata[256];
  float a = (float)alpha[0];
  float kT = (0.5f <= a) ? 0.5f : a;
  float hold = kT * inv_ord(maxacc[which]);
  float s = 0.f;
  for (int i = blockIdx.x * 256 + threadIdx.x; i < P; i += gridDim.x * 256) {
    float v = l[i];
    if (!(v > hold)) s += v;
  }
  sdata[threadIdx.x] = s;
  __syncthreads();
  for (int off = 128; off; off >>= 1) {
    if (threadIdx.x < off) sdata[threadIdx.x] += sdata[threadIdx.x + off];
    __syncthreads();
  }
  if (threadIdx.x == 0) atomicAdd(&sums[which], sdata[0]);
}

__global__ void final_kernel(const float* __restrict__ sums, float* __restrict__ out) {
  out[0] = -(sums[0] + sums[1]);
}

extern "C" void kernel_launch(void* const* d_in, const int* in_sizes, int n_in,
                              void* d_out, int out_size, void* d_ws, size_t ws_size,
                              hipStream_t stream) {
  const float* feat_user = (const float*)d_in[0];
  const float* feat_item = (const float*)d_in[1];
  const float* W_user = (const float*)d_in[2];
  const float* b_user = (const float*)d_in[3];
  const float* W_item = (const float*)d_in[4];
  const float* b_item = (const float*)d_in[5];
  const float* W_gat = (const float*)d_in[6];
  const float* attn_l = (const float*)d_in[7];
  const float* attn_r = (const float*)d_in[8];
  const float* gat_bias = (const float*)d_in[9];
  const float* W_pred = (const float*)d_in[10];
  const float* b_pred = (const float*)d_in[11];
  const int* src = (const int*)d_in[12];
  const int* dst = (const int*)d_in[13];
  const int* pos_src = (const int*)d_in[14];
  const int* pos_dst = (const int*)d_in[15];
  const int* neg_src = (const int*)d_in[16];
  const int* neg_dst = (const int*)d_in[17];
  const int* alpha = (const int*)d_in[18];
  const int E = in_sizes[12];
  const int P = in_sizes[14];

  // ---- workspace layout
  char* p = (char*)d_ws;
  auto alloc = [&](size_t bytes) {
    char* r = p;
    p += (bytes + 255) & ~(size_t)255;
    return r;
  };
  __hip_bfloat16* z = (__hip_bfloat16*)alloc((size_t)NNODE * 128 * 2);
  __hip_bfloat16* h = (__hip_bfloat16*)alloc((size_t)NNODE * 128 * 2);
  float* el = (float*)alloc((size_t)NNODE * 4);
  float* er = (float*)alloc((size_t)NNODE * 4);
  float* Wf_u = (float*)alloc(256 * 128 * 4);
  float* bf_u = (float*)alloc(128 * 4);
  float* Wf_i = (float*)alloc(128 * 128 * 4);
  float* bf_i = (float*)alloc(128 * 4);
  __hip_bfloat16* Bp_u = (__hip_bfloat16*)alloc(256 * 128 * 2);
  __hip_bfloat16* Bp_i = (__hip_bfloat16*)alloc(128 * 128 * 2);
  __hip_bfloat16* Bp_p = (__hip_bfloat16*)alloc(128 * 64 * 2);
  int* offs = (int*)alloc((size_t)(NNODE + 4) * 4);
  int* ssrc = (int*)alloc((size_t)E * 4);
  float* l_pos = (float*)alloc((size_t)P * 4);
  float* l_neg = (float*)alloc((size_t)P * 4);
  int* bsum = (int*)alloc(512 * 4);
  // zero region (one memset): deg | cursor | maxacc[2] | sums[2]
  int* deg = (int*)alloc((size_t)(2 * NNODE + 8) * 4);
  int* cursor = deg + NNODE;
  unsigned int* maxacc = (unsigned int*)(cursor + NNODE);
  float* sums = (float*)(maxacc + 2);

  float* out_loss = (float*)d_out;
  float* out_pred = out_loss + 1;

  hipMemsetAsync(deg, 0, (size_t)(2 * NNODE + 8) * 4, stream);

  // weight fusion + fragment packing
  fusew_kernel<<<257, 128, 0, stream>>>(W_user, b_user, W_gat, Wf_u, bf_u, 256);
  fusew_kernel<<<129, 128, 0, stream>>>(W_item, b_item, W_gat, Wf_i, bf_i, 128);
  packb_kernel<<<(256 * 128 + 255) / 256, 256, 0, stream>>>(Wf_u, Bp_u, 256, 128);
  packb_kernel<<<(128 * 128 + 255) / 256, 256, 0, stream>>>(Wf_i, Bp_i, 128, 128);
  packb_kernel<<<(128 * 64 + 255) / 256, 256, 0, stream>>>(W_pred, Bp_p, 128, 64);

  // CSR by dst (overlappable with GEMMs in stream order; launched first-come)
  int egrid = (E + 255) / 256;
  hist_kernel<<<egrid, 256, 0, stream>>>(dst, deg, E);
  int ngrid = (NNODE + 255) / 256;
  scan1_kernel<<<ngrid, 256, 0, stream>>>(deg, offs, bsum, NNODE);
  scan2_kernel<<<1, 512, 0, stream>>>(bsum, ngrid);
  scan3_kernel<<<ngrid, 256, 0, stream>>>(offs, bsum, NNODE);
  scatter_kernel<<<egrid, 256, 0, stream>>>(src, dst, offs, cursor, ssrc, E);

  // z = feat @ Wf + bf (bf16 MFMA, fused el/er epilogue)
  zgemm_kernel<256><<<(NUSER + 63) / 64, 256, 0, stream>>>(feat_user, Bp_u, bf_u, attn_l, attn_r,
                                                           z, el, er, NUSER);
  zgemm_kernel<128><<<(NITEM + 63) / 64, 256, 0, stream>>>(feat_item, Bp_i, bf_i, attn_l, attn_r,
                                                           z + (size_t)NUSER * 128, el + NUSER,
                                                           er + NUSER, NITEM);

  // GAT edge-softmax aggregation -> h (bf16)
  aggregate_kernel<<<NNODE / 4, 256, 0, stream>>>(z, el, er, offs, ssrc, gat_bias, h);

  // link scores + loss
  score_kernel<<<1024, 256, 0, stream>>>(h, pos_src, pos_dst, l_pos, maxacc + 0, P);
  score_kernel<<<1024, 256, 0, stream>>>(h, neg_src, neg_dst, l_neg, maxacc + 1, P);
  loss_sum_kernel<<<512, 256, 0, stream>>>(l_pos, maxacc, alpha, 0, sums, P);
  loss_sum_kernel<<<512, 256, 0, stream>>>(l_neg, maxacc, alpha, 1, sums, P);
  final_kernel<<<1, 1, 0, stream>>>(sums, out_loss);

  // prediction head: out = h[:NUSER] @ W_pred + b_pred (bf16 MFMA)
  predgemm_kernel<<<(NUSER + 63) / 64, 256, 0, stream>>>(h, Bp_p, b_pred, out_pred, NUSER);

  (void)n_in; (void)out_size; (void)ws_size;
}

// Round 3
// 461.667 us; speedup vs baseline: 2.1067x; 1.1246x over previous
//
#include <hip/hip_runtime.h>
#include <hip/hip_bf16.h>
#include <math.h>

#define NUSER 60000
#define NITEM 60000
#define NNODE 120000

typedef __attribute__((ext_vector_type(8))) short bf16x8;
typedef __attribute__((ext_vector_type(4))) float f32x4;
typedef __attribute__((ext_vector_type(8))) unsigned short u16x8;
typedef __attribute__((ext_vector_type(4))) unsigned short u16x4;

__device__ __forceinline__ float leaky02(float x) { return x > 0.f ? x : 0.2f * x; }

__device__ __forceinline__ float inv_ord(unsigned int u) {
  unsigned int bits = (u & 0x80000000u) ? (u & 0x7FFFFFFFu) : ~u;
  return __uint_as_float(bits);
}
__device__ __forceinline__ unsigned int ord_of(float f) {
  unsigned int u = __float_as_uint(f);
  return (u & 0x80000000u) ? ~u : (u | 0x80000000u);
}
__device__ __forceinline__ short f2bs(float f) {
  __hip_bfloat16 h = __float2bfloat16(f);
  return *reinterpret_cast<short*>(&h);
}
__device__ __forceinline__ float bf2f(unsigned short u) {
  union { unsigned int u32; float f; } x;
  x.u32 = ((unsigned int)u) << 16;
  return x.f;
}

// ---- fused weights: Wf[r][n] = sum_j Wa[r][j] * Wg[j][n];  bf[n] = sum_j ba[j] * Wg[j][n]
__global__ void fusew_kernel(const float* __restrict__ Wa, const float* __restrict__ ba,
                             const float* __restrict__ Wg, float* __restrict__ Wf,
                             float* __restrict__ bf, int K) {
  int n = threadIdx.x;
  int r = blockIdx.x;
  if (r < K) {
    float acc = 0.f;
#pragma unroll 8
    for (int j = 0; j < 128; ++j) acc = fmaf(Wa[r * 128 + j], Wg[j * 128 + n], acc);
    Wf[r * 128 + n] = acc;
  } else {
    float acc = 0.f;
    for (int j = 0; j < 128; ++j) acc = fmaf(ba[j], Wg[j * 128 + n], acc);
    bf[n] = acc;
  }
}

// ---- pack W (fp32 [K][N]) into MFMA B-fragment layout, bf16.
__global__ void packb_kernel(const float* __restrict__ W, __hip_bfloat16* __restrict__ Bp,
                             int K, int N) {
  int t = blockIdx.x * 256 + threadIdx.x;
  if (t >= K * N) return;
  int j = t & 7;
  int lane = (t >> 3) & 63;
  int rest = t >> 9;
  int NT = N >> 4;
  int nt = rest % NT;
  int ks = rest / NT;
  int k = ks * 32 + ((lane >> 4) << 3) + j;
  int n = nt * 16 + (lane & 15);
  Bp[t] = __float2bfloat16(W[k * N + n]);
}

// ---- z GEMM with LDS-staged A (coalesced fp32 reads -> bf16 swizzled LDS) + fused el/er.
template <int K>
__global__ __launch_bounds__(256) void zgemm_kernel(
    const float* __restrict__ A, const __hip_bfloat16* __restrict__ Bp,
    const float* __restrict__ bias, const float* __restrict__ al, const float* __restrict__ ar,
    __hip_bfloat16* __restrict__ z, float* __restrict__ el, float* __restrict__ er, int M) {
  __shared__ __align__(16) char smem[64 * 140 * 4];  // 35840 B; A-tile (<=32KB) then epilogue
  unsigned short* As = (unsigned short*)smem;
  float(*lds)[140] = (float(*)[140])smem;
  const int lane = threadIdx.x & 63, wv = threadIdx.x >> 6;
  const int t = threadIdx.x;
  // stage A: 64 rows x K fp32 -> bf16 LDS, XOR-swizzled rows
  const int C4 = K / 4;
  for (int f = t; f < 64 * C4; f += 256) {
    int row = f / C4, c4 = f - row * C4;
    int grow = blockIdx.x * 64 + row;
    if (grow >= M) grow = M - 1;
    float4 a = *(const float4*)(A + (size_t)grow * K + c4 * 4);
    u16x4 pk;
    pk[0] = (unsigned short)f2bs(a.x);
    pk[1] = (unsigned short)f2bs(a.y);
    pk[2] = (unsigned short)f2bs(a.z);
    pk[3] = (unsigned short)f2bs(a.w);
    unsigned int byte = (unsigned int)row * (K * 2) + (unsigned int)c4 * 8;
    byte ^= (row & 7) << 4;
    *(u16x4*)(smem + byte) = pk;
  }
  __syncthreads();
  // MFMA from LDS A-frags
  const bf16x8* bp = (const bf16x8*)Bp;
  const int frow = wv * 16 + (lane & 15);
  f32x4 acc[8] = {};
#pragma unroll
  for (int ks = 0; ks < K / 32; ++ks) {
    unsigned int byte = (unsigned int)frow * (K * 2) + (unsigned int)(ks * 32 + ((lane >> 4) << 3)) * 2;
    byte ^= (frow & 7) << 4;
    bf16x8 af = *(const bf16x8*)(smem + byte);
#pragma unroll
    for (int nt = 0; nt < 8; ++nt) {
      bf16x8 bfr = bp[(ks * 8 + nt) * 64 + lane];
      acc[nt] = __builtin_amdgcn_mfma_f32_16x16x32_bf16(af, bfr, acc[nt], 0, 0, 0);
    }
  }
  __syncthreads();
  // epilogue: acc -> lds rows (C layout m89: row=(lane>>4)*4+r, col=lane&15)
#pragma unroll
  for (int nt = 0; nt < 8; ++nt) {
    float b = bias[nt * 16 + (lane & 15)];
#pragma unroll
    for (int r = 0; r < 4; ++r)
      lds[wv * 16 + (lane >> 4) * 4 + r][nt * 16 + (lane & 15)] = acc[nt][r] + b;
  }
  __syncthreads();
  // phase 2: row-major readout -> bf16 z + fused el/er
  int row = threadIdx.x >> 2;
  int q = threadIdx.x & 3;
  int gm = blockIdx.x * 64 + row;
  float pl = 0.f, pr = 0.f;
  if (gm < M) {
    const float* lrow = &lds[row][q * 32];
#pragma unroll
    for (int v4 = 0; v4 < 4; ++v4) {
      u16x8 outv;
#pragma unroll
      for (int j = 0; j < 8; ++j) {
        float f = lrow[v4 * 8 + j];
        int c = q * 32 + v4 * 8 + j;
        pl = fmaf(f, al[c], pl);
        pr = fmaf(f, ar[c], pr);
        outv[j] = (unsigned short)f2bs(f);
      }
      *(u16x8*)((unsigned short*)z + (size_t)gm * 128 + q * 32 + v4 * 8) = outv;
    }
  }
  pl += __shfl_xor(pl, 1, 64); pl += __shfl_xor(pl, 2, 64);
  pr += __shfl_xor(pr, 1, 64); pr += __shfl_xor(pr, 2, 64);
  if (q == 0 && gm < M) { el[gm] = pl; er[gm] = pr; }
}

// ---- pred GEMM: out[M][64] (fp32) = h[M][128] (bf16) @ Bp(W_pred packed) + b_pred
__global__ __launch_bounds__(256) void predgemm_kernel(
    const __hip_bfloat16* __restrict__ h, const __hip_bfloat16* __restrict__ Bp,
    const float* __restrict__ bias, float* __restrict__ out, int M) {
  const int lane = threadIdx.x & 63, wv = threadIdx.x >> 6;
  const int m0 = blockIdx.x * 64 + wv * 16;
  int arow = m0 + (lane & 15);
  if (arow >= M) arow = M - 1;
  const bf16x8* a0 = (const bf16x8*)(h + (size_t)arow * 128) + (lane >> 4);
  const bf16x8* bp = (const bf16x8*)Bp;
  f32x4 acc[4] = {};
#pragma unroll
  for (int ks = 0; ks < 4; ++ks) {
    bf16x8 af = a0[ks * 4];
#pragma unroll
    for (int nt = 0; nt < 4; ++nt) {
      bf16x8 bfr = bp[(ks * 4 + nt) * 64 + lane];
      acc[nt] = __builtin_amdgcn_mfma_f32_16x16x32_bf16(af, bfr, acc[nt], 0, 0, 0);
    }
  }
#pragma unroll
  for (int nt = 0; nt < 4; ++nt) {
    int col = nt * 16 + (lane & 15);
    float b = bias[col];
#pragma unroll
    for (int r = 0; r < 4; ++r) {
      int m = m0 + (lane >> 4) * 4 + r;
      if (m < M) out[(size_t)m * 64 + col] = acc[nt][r] + b;
    }
  }
}

// ---- degree histogram
__global__ void hist_kernel(const int* __restrict__ dst, int* __restrict__ deg, int E) {
  int i = blockIdx.x * blockDim.x + threadIdx.x;
  if (i < E) atomicAdd(&deg[dst[i]], 1);
}

// ---- 3-kernel exclusive scan -> offsets[N+1]
__global__ void scan1_kernel(const int* __restrict__ deg, int* __restrict__ offs,
                             int* __restrict__ bsum, int N) {
  __shared__ int s[256];
  int t = threadIdx.x;
  int i = blockIdx.x * 256 + t;
  int v = (i < N) ? deg[i] : 0;
  s[t] = v;
  __syncthreads();
  for (int off = 1; off < 256; off <<= 1) {
    int add = (t >= off) ? s[t - off] : 0;
    __syncthreads();
    s[t] += add;
    __syncthreads();
  }
  if (i < N) offs[i + 1] = s[t];
  if (t == 255) bsum[blockIdx.x] = s[255];
  if (i == 0) offs[0] = 0;
}
__global__ void scan2_kernel(int* __restrict__ bsum, int NB) {
  __shared__ int s[512];
  int t = threadIdx.x;
  s[t] = (t < NB) ? bsum[t] : 0;
  __syncthreads();
  for (int off = 1; off < 512; off <<= 1) {
    int add = (t >= off) ? s[t - off] : 0;
    __syncthreads();
    s[t] += add;
    __syncthreads();
  }
  if (t < NB) bsum[t] = s[t];
}
__global__ void scan3_kernel(int* __restrict__ offs, const int* __restrict__ bsum, int N) {
  int b = blockIdx.x;
  int i = b * 256 + threadIdx.x;
  if (b > 0 && i < N) offs[i + 1] += bsum[b - 1];
}

// ---- scatter edges into dst-sorted order (store src only)
__global__ void scatter_kernel(const int* __restrict__ src, const int* __restrict__ dst,
                               const int* __restrict__ offs, int* __restrict__ cursor,
                               int* __restrict__ ssrc, int E) {
  int i = blockIdx.x * blockDim.x + threadIdx.x;
  if (i < E) {
    int d = dst[i];
    int p = atomicAdd(&cursor[d], 1);
    ssrc[offs[d] + p] = src[i];
  }
}

// ---- GAT aggregation: one wave per dst node; softmax precomputed, (w,src) via LDS broadcast.
__global__ __launch_bounds__(256) void aggregate_kernel(
    const __hip_bfloat16* __restrict__ z, const float* __restrict__ el,
    const float* __restrict__ er, const int* __restrict__ offs, const int* __restrict__ ssrc,
    const float* __restrict__ gat_bias, __hip_bfloat16* __restrict__ h) {
  __shared__ __align__(16) float2 ew[4][128];
  int wv = threadIdx.x >> 6, lane = threadIdx.x & 63;
  int d = blockIdx.x * 4 + wv;
  int s0 = offs[d], s1 = offs[d + 1];
  int deg = s1 - s0;
  float erd = er[d];
  float e0 = -1e30f, e1 = -1e30f;
  int src0 = 0, src1 = 0;
  if (lane < deg) { src0 = ssrc[s0 + lane]; e0 = leaky02(el[src0] + erd); }
  if (64 + lane < deg) { src1 = ssrc[s0 + 64 + lane]; e1 = leaky02(el[src1] + erd); }
  float m = fmaxf(e0, e1);
  for (int i = s0 + 128 + lane; i < s1; i += 64) m = fmaxf(m, leaky02(el[ssrc[i]] + erd));
#pragma unroll
  for (int mm = 32; mm; mm >>= 1) m = fmaxf(m, __shfl_xor(m, mm, 64));

  const ushort2* zb2 = (const ushort2*)z;  // row stride 64 (ushort2 units)
  float acc0 = 0.f, acc1 = 0.f, ssum;
  if (deg <= 128) {
    float w0 = (lane < deg) ? __expf(e0 - m) : 0.f;
    float w1 = (64 + lane < deg) ? __expf(e1 - m) : 0.f;
    ssum = w0 + w1;
#pragma unroll
    for (int mm = 32; mm; mm >>= 1) ssum += __shfl_xor(ssum, mm, 64);
    ew[wv][lane] = make_float2(w0, __int_as_float(src0));
    ew[wv][64 + lane] = make_float2(w1, __int_as_float(src1));
    __builtin_amdgcn_wave_barrier();
    int i = 0;
    for (; i + 4 <= deg; i += 4) {
      float4 pA = *(const float4*)&ew[wv][i];
      float4 pB = *(const float4*)&ew[wv][i + 2];
      unsigned int oA = ((unsigned int)__float_as_uint(pA.y) << 6) + lane;
      unsigned int oB = ((unsigned int)__float_as_uint(pA.w) << 6) + lane;
      unsigned int oC = ((unsigned int)__float_as_uint(pB.y) << 6) + lane;
      unsigned int oD = ((unsigned int)__float_as_uint(pB.w) << 6) + lane;
      ushort2 vA = zb2[oA];
      ushort2 vB = zb2[oB];
      ushort2 vC = zb2[oC];
      ushort2 vD = zb2[oD];
      acc0 = fmaf(pA.x, bf2f(vA.x), acc0); acc1 = fmaf(pA.x, bf2f(vA.y), acc1);
      acc0 = fmaf(pA.z, bf2f(vB.x), acc0); acc1 = fmaf(pA.z, bf2f(vB.y), acc1);
      acc0 = fmaf(pB.x, bf2f(vC.x), acc0); acc1 = fmaf(pB.x, bf2f(vC.y), acc1);
      acc0 = fmaf(pB.z, bf2f(vD.x), acc0); acc1 = fmaf(pB.z, bf2f(vD.y), acc1);
    }
    for (; i < deg; ++i) {
      float2 p = ew[wv][i];
      unsigned int o = ((unsigned int)__float_as_uint(p.y) << 6) + lane;
      ushort2 v = zb2[o];
      acc0 = fmaf(p.x, bf2f(v.x), acc0);
      acc1 = fmaf(p.x, bf2f(v.y), acc1);
    }
  } else {
    ssum = 0.f;
    for (int i = s0; i < s1; ++i) {
      int s = ssrc[i];
      float w = __expf(leaky02(el[s] + erd) - m);
      ssum += w;
      ushort2 cur = zb2[((unsigned int)s << 6) + lane];
      acc0 = fmaf(w, bf2f(cur.x), acc0);
      acc1 = fmaf(w, bf2f(cur.y), acc1);
    }
  }
  float inv = 1.f / ssum;
  float o0 = acc0 * inv + gat_bias[lane * 2];
  float o1 = acc1 * inv + gat_bias[lane * 2 + 1];
  o0 = (o0 > 0.f) ? o0 : (__expf(o0) - 1.f);
  o1 = (o1 > 0.f) ? o1 : (__expf(o1) - 1.f);
  ushort2 ov;
  ov.x = (unsigned short)f2bs(o0);
  ov.y = (unsigned short)f2bs(o1);
  *(ushort2*)((unsigned short*)h + (size_t)d * 128 + lane * 2) = ov;
}

// ---- link scores -> log_sigmoid, store l, track max (ordered-uint atomicMax)
__global__ __launch_bounds__(256) void score_kernel(const __hip_bfloat16* __restrict__ h,
                                                    const int* __restrict__ sa,
                                                    const int* __restrict__ sb,
                                                    float* __restrict__ lout,
                                                    unsigned int* __restrict__ maxacc, int P) {
  __shared__ float wmax[4];
  int lane = threadIdx.x & 63, wv = threadIdx.x >> 6;
  const ushort2* h2 = (const ushort2*)h;
  float lmax = -1e30f;
  for (int i = blockIdx.x * 4 + wv; i < P; i += gridDim.x * 4) {
    int a = sa[i], b = sb[i];
    ushort2 va = h2[((unsigned int)a << 6) + lane];
    ushort2 vb = h2[((unsigned int)b << 6) + lane];
    float s = bf2f(va.x) * bf2f(vb.x) + bf2f(va.y) * bf2f(vb.y);
#pragma unroll
    for (int mm = 32; mm; mm >>= 1) s += __shfl_xor(s, mm, 64);
    float l = fminf(s, 0.f) - log1pf(__expf(-fabsf(s)));
    if (lane == 0) lout[i] = l;
    lmax = fmaxf(lmax, l);
  }
  if (lane == 0) wmax[wv] = lmax;
  __syncthreads();
  if (threadIdx.x == 0) {
    float bm = fmaxf(fmaxf(wmax[0], wmax[1]), fmaxf(wmax[2], wmax[3]));
    atomicMax(maxacc, ord_of(bm));
  }
}

// ---- thresholded sum: sum of l where !(l > hold), hold = k_T * max(l)
__global__ __launch_bounds__(256) void loss_sum_kernel(const float* __restrict__ l,
                                                       const unsigned int* __restrict__ maxacc,
                                                       const int* __restrict__ alpha, int which,
                                                       float* __restrict__ sums, int P) {
  __shared__ float sdata[256];
  float a = (float)alpha[0];
  float kT = (0.5f <= a) ? 0.5f : a;
  float hold = kT * inv_ord(maxacc[which]);
  float s = 0.f;
  for (int i = blockIdx.x * 256 + threadIdx.x; i < P; i += gridDim.x * 256) {
    float v = l[i];
    if (!(v > hold)) s += v;
  }
  sdata[threadIdx.x] = s;
  __syncthreads();
  for (int off = 128; off; off >>= 1) {
    if (threadIdx.x < off) sdata[threadIdx.x] += sdata[threadIdx.x + off];
    __syncthreads();
  }
  if (threadIdx.x == 0) atomicAdd(&sums[which], sdata[0]);
}

__global__ void final_kernel(const float* __restrict__ sums, float* __restrict__ out) {
  out[0] = -(sums[0] + sums[1]);
}

extern "C" void kernel_launch(void* const* d_in, const int* in_sizes, int n_in,
                              void* d_out, int out_size, void* d_ws, size_t ws_size,
                              hipStream_t stream) {
  const float* feat_user = (const float*)d_in[0];
  const float* feat_item = (const float*)d_in[1];
  const float* W_user = (const float*)d_in[2];
  const float* b_user = (const float*)d_in[3];
  const float* W_item = (const float*)d_in[4];
  const float* b_item = (const float*)d_in[5];
  const float* W_gat = (const float*)d_in[6];
  const float* attn_l = (const float*)d_in[7];
  const float* attn_r = (const float*)d_in[8];
  const float* gat_bias = (const float*)d_in[9];
  const float* W_pred = (const float*)d_in[10];
  const float* b_pred = (const float*)d_in[11];
  const int* src = (const int*)d_in[12];
  const int* dst = (const int*)d_in[13];
  const int* pos_src = (const int*)d_in[14];
  const int* pos_dst = (const int*)d_in[15];
  const int* neg_src = (const int*)d_in[16];
  const int* neg_dst = (const int*)d_in[17];
  const int* alpha = (const int*)d_in[18];
  const int E = in_sizes[12];
  const int P = in_sizes[14];

  char* p = (char*)d_ws;
  auto alloc = [&](size_t bytes) {
    char* r = p;
    p += (bytes + 255) & ~(size_t)255;
    return r;
  };
  __hip_bfloat16* z = (__hip_bfloat16*)alloc((size_t)NNODE * 128 * 2);
  __hip_bfloat16* h = (__hip_bfloat16*)alloc((size_t)NNODE * 128 * 2);
  float* el = (float*)alloc((size_t)NNODE * 4);
  float* er = (float*)alloc((size_t)NNODE * 4);
  float* Wf_u = (float*)alloc(256 * 128 * 4);
  float* bf_u = (float*)alloc(128 * 4);
  float* Wf_i = (float*)alloc(128 * 128 * 4);
  float* bf_i = (float*)alloc(128 * 4);
  __hip_bfloat16* Bp_u = (__hip_bfloat16*)alloc(256 * 128 * 2);
  __hip_bfloat16* Bp_i = (__hip_bfloat16*)alloc(128 * 128 * 2);
  __hip_bfloat16* Bp_p = (__hip_bfloat16*)alloc(128 * 64 * 2);
  int* offs = (int*)alloc((size_t)(NNODE + 4) * 4);
  int* ssrc = (int*)alloc((size_t)E * 4);
  float* l_pos = (float*)alloc((size_t)P * 4);
  float* l_neg = (float*)alloc((size_t)P * 4);
  int* bsum = (int*)alloc(512 * 4);
  int* deg = (int*)alloc((size_t)(2 * NNODE + 8) * 4);
  int* cursor = deg + NNODE;
  unsigned int* maxacc = (unsigned int*)(cursor + NNODE);
  float* sums = (float*)(maxacc + 2);

  float* out_loss = (float*)d_out;
  float* out_pred = out_loss + 1;

  hipMemsetAsync(deg, 0, (size_t)(2 * NNODE + 8) * 4, stream);

  fusew_kernel<<<257, 128, 0, stream>>>(W_user, b_user, W_gat, Wf_u, bf_u, 256);
  fusew_kernel<<<129, 128, 0, stream>>>(W_item, b_item, W_gat, Wf_i, bf_i, 128);
  packb_kernel<<<(256 * 128 + 255) / 256, 256, 0, stream>>>(Wf_u, Bp_u, 256, 128);
  packb_kernel<<<(128 * 128 + 255) / 256, 256, 0, stream>>>(Wf_i, Bp_i, 128, 128);
  packb_kernel<<<(128 * 64 + 255) / 256, 256, 0, stream>>>(W_pred, Bp_p, 128, 64);

  int egrid = (E + 255) / 256;
  hist_kernel<<<egrid, 256, 0, stream>>>(dst, deg, E);
  int ngrid = (NNODE + 255) / 256;
  scan1_kernel<<<ngrid, 256, 0, stream>>>(deg, offs, bsum, NNODE);
  scan2_kernel<<<1, 512, 0, stream>>>(bsum, ngrid);
  scan3_kernel<<<ngrid, 256, 0, stream>>>(offs, bsum, NNODE);
  scatter_kernel<<<egrid, 256, 0, stream>>>(src, dst, offs, cursor, ssrc, E);

  zgemm_kernel<256><<<(NUSER + 63) / 64, 256, 0, stream>>>(feat_user, Bp_u, bf_u, attn_l, attn_r,
                                                           z, el, er, NUSER);
  zgemm_kernel<128><<<(NITEM + 63) / 64, 256, 0, stream>>>(feat_item, Bp_i, bf_i, attn_l, attn_r,
                                                           z + (size_t)NUSER * 128, el + NUSER,
                                                           er + NUSER, NITEM);

  aggregate_kernel<<<NNODE / 4, 256, 0, stream>>>(z, el, er, offs, ssrc, gat_bias, h);

  score_kernel<<<2048, 256, 0, stream>>>(h, pos_src, pos_dst, l_pos, maxacc + 0, P);
  score_kernel<<<2048, 256, 0, stream>>>(h, neg_src, neg_dst, l_neg, maxacc + 1, P);
  loss_sum_kernel<<<512, 256, 0, stream>>>(l_pos, maxacc, alpha, 0, sums, P);
  loss_sum_kernel<<<512, 256, 0, stream>>>(l_neg, maxacc, alpha, 1, sums, P);
  final_kernel<<<1, 1, 0, stream>>>(sums, out_loss);

  predgemm_kernel<<<(NUSER + 63) / 64, 256, 0, stream>>>(h, Bp_p, b_pred, out_pred, NUSER);

  (void)n_in; (void)out_size; (void)ws_size;
}

// Round 4
// 340.371 us; speedup vs baseline: 2.8574x; 1.3564x over previous
//
#include <hip/hip_runtime.h>
#include <hip/hip_bf16.h>
#include <math.h>

#define NUSER 60000
#define NITEM 60000
#define NNODE 120000
#define BSH 9
#define NB 235           // ceil(NNODE / 512)
#define CAP 8192         // per-bucket LDS capacity (mean ~6.9k, sigma ~83)

typedef __attribute__((ext_vector_type(8))) short bf16x8;
typedef __attribute__((ext_vector_type(4))) float f32x4;
typedef __attribute__((ext_vector_type(8))) unsigned short u16x8;
typedef __attribute__((ext_vector_type(4))) unsigned short u16x4;

__device__ __forceinline__ float leaky02(float x) { return x > 0.f ? x : 0.2f * x; }

__device__ __forceinline__ float inv_ord(unsigned int u) {
  unsigned int bits = (u & 0x80000000u) ? (u & 0x7FFFFFFFu) : ~u;
  return __uint_as_float(bits);
}
__device__ __forceinline__ unsigned int ord_of(float f) {
  unsigned int u = __float_as_uint(f);
  return (u & 0x80000000u) ? ~u : (u | 0x80000000u);
}
__device__ __forceinline__ short f2bs(float f) {
  __hip_bfloat16 h = __float2bfloat16(f);
  return *reinterpret_cast<short*>(&h);
}
__device__ __forceinline__ float bf2f(unsigned short u) {
  union { unsigned int u32; float f; } x;
  x.u32 = ((unsigned int)u) << 16;
  return x.f;
}

// ---- fused weights: Wf[r][n] = sum_j Wa[r][j] * Wg[j][n];  bf[n] = sum_j ba[j] * Wg[j][n]
__global__ void fusew_kernel(const float* __restrict__ Wa, const float* __restrict__ ba,
                             const float* __restrict__ Wg, float* __restrict__ Wf,
                             float* __restrict__ bf, int K) {
  int n = threadIdx.x;
  int r = blockIdx.x;
  if (r < K) {
    float acc = 0.f;
#pragma unroll 8
    for (int j = 0; j < 128; ++j) acc = fmaf(Wa[r * 128 + j], Wg[j * 128 + n], acc);
    Wf[r * 128 + n] = acc;
  } else {
    float acc = 0.f;
    for (int j = 0; j < 128; ++j) acc = fmaf(ba[j], Wg[j * 128 + n], acc);
    bf[n] = acc;
  }
}

// ---- pack W (fp32 [K][N]) into MFMA B-fragment layout, bf16.
__global__ void packb_kernel(const float* __restrict__ W, __hip_bfloat16* __restrict__ Bp,
                             int K, int N) {
  int t = blockIdx.x * 256 + threadIdx.x;
  if (t >= K * N) return;
  int j = t & 7;
  int lane = (t >> 3) & 63;
  int rest = t >> 9;
  int NT = N >> 4;
  int nt = rest % NT;
  int ks = rest / NT;
  int k = ks * 32 + ((lane >> 4) << 3) + j;
  int n = nt * 16 + (lane & 15);
  Bp[t] = __float2bfloat16(W[k * N + n]);
}

// ---- z GEMM with LDS-staged A (coalesced fp32 reads -> bf16 swizzled LDS) + fused el/er.
template <int K>
__global__ __launch_bounds__(256) void zgemm_kernel(
    const float* __restrict__ A, const __hip_bfloat16* __restrict__ Bp,
    const float* __restrict__ bias, const float* __restrict__ al, const float* __restrict__ ar,
    __hip_bfloat16* __restrict__ z, float* __restrict__ el, float* __restrict__ er, int M) {
  __shared__ __align__(16) char smem[64 * 140 * 4];
  float(*lds)[140] = (float(*)[140])smem;
  const int lane = threadIdx.x & 63, wv = threadIdx.x >> 6;
  const int t = threadIdx.x;
  const int C4 = K / 4;
  for (int f = t; f < 64 * C4; f += 256) {
    int row = f / C4, c4 = f - row * C4;
    int grow = blockIdx.x * 64 + row;
    if (grow >= M) grow = M - 1;
    float4 a = *(const float4*)(A + (size_t)grow * K + c4 * 4);
    u16x4 pk;
    pk[0] = (unsigned short)f2bs(a.x);
    pk[1] = (unsigned short)f2bs(a.y);
    pk[2] = (unsigned short)f2bs(a.z);
    pk[3] = (unsigned short)f2bs(a.w);
    unsigned int byte = (unsigned int)row * (K * 2) + (unsigned int)c4 * 8;
    byte ^= (row & 7) << 4;
    *(u16x4*)(smem + byte) = pk;
  }
  __syncthreads();
  const bf16x8* bp = (const bf16x8*)Bp;
  const int frow = wv * 16 + (lane & 15);
  f32x4 acc[8] = {};
#pragma unroll
  for (int ks = 0; ks < K / 32; ++ks) {
    unsigned int byte = (unsigned int)frow * (K * 2) + (unsigned int)(ks * 32 + ((lane >> 4) << 3)) * 2;
    byte ^= (frow & 7) << 4;
    bf16x8 af = *(const bf16x8*)(smem + byte);
#pragma unroll
    for (int nt = 0; nt < 8; ++nt) {
      bf16x8 bfr = bp[(ks * 8 + nt) * 64 + lane];
      acc[nt] = __builtin_amdgcn_mfma_f32_16x16x32_bf16(af, bfr, acc[nt], 0, 0, 0);
    }
  }
  __syncthreads();
#pragma unroll
  for (int nt = 0; nt < 8; ++nt) {
    float b = bias[nt * 16 + (lane & 15)];
#pragma unroll
    for (int r = 0; r < 4; ++r)
      lds[wv * 16 + (lane >> 4) * 4 + r][nt * 16 + (lane & 15)] = acc[nt][r] + b;
  }
  __syncthreads();
  int row = threadIdx.x >> 2;
  int q = threadIdx.x & 3;
  int gm = blockIdx.x * 64 + row;
  float pl = 0.f, pr = 0.f;
  if (gm < M) {
    const float* lrow = &lds[row][q * 32];
#pragma unroll
    for (int v4 = 0; v4 < 4; ++v4) {
      u16x8 outv;
#pragma unroll
      for (int j = 0; j < 8; ++j) {
        float f = lrow[v4 * 8 + j];
        int c = q * 32 + v4 * 8 + j;
        pl = fmaf(f, al[c], pl);
        pr = fmaf(f, ar[c], pr);
        outv[j] = (unsigned short)f2bs(f);
      }
      *(u16x8*)((unsigned short*)z + (size_t)gm * 128 + q * 32 + v4 * 8) = outv;
    }
  }
  pl += __shfl_xor(pl, 1, 64); pl += __shfl_xor(pl, 2, 64);
  pr += __shfl_xor(pr, 1, 64); pr += __shfl_xor(pr, 2, 64);
  if (q == 0 && gm < M) { el[gm] = pl; er[gm] = pr; }
}

// ---- pred GEMM: out[M][64] (fp32) = h[M][128] (bf16) @ Bp(W_pred packed) + b_pred
__global__ __launch_bounds__(256) void predgemm_kernel(
    const __hip_bfloat16* __restrict__ h, const __hip_bfloat16* __restrict__ Bp,
    const float* __restrict__ bias, float* __restrict__ out, int M) {
  const int lane = threadIdx.x & 63, wv = threadIdx.x >> 6;
  const int m0 = blockIdx.x * 64 + wv * 16;
  int arow = m0 + (lane & 15);
  if (arow >= M) arow = M - 1;
  const bf16x8* a0 = (const bf16x8*)(h + (size_t)arow * 128) + (lane >> 4);
  const bf16x8* bp = (const bf16x8*)Bp;
  f32x4 acc[4] = {};
#pragma unroll
  for (int ks = 0; ks < 4; ++ks) {
    bf16x8 af = a0[ks * 4];
#pragma unroll
    for (int nt = 0; nt < 4; ++nt) {
      bf16x8 bfr = bp[(ks * 4 + nt) * 64 + lane];
      acc[nt] = __builtin_amdgcn_mfma_f32_16x16x32_bf16(af, bfr, acc[nt], 0, 0, 0);
    }
  }
#pragma unroll
  for (int nt = 0; nt < 4; ++nt) {
    int col = nt * 16 + (lane & 15);
    float b = bias[col];
#pragma unroll
    for (int r = 0; r < 4; ++r) {
      int m = m0 + (lane >> 4) * 4 + r;
      if (m < M) out[(size_t)m * 64 + col] = acc[nt][r] + b;
    }
  }
}

// ---- CSR build, stage 0: bucket counts (LDS histogram, one global add per block-bucket)
__global__ __launch_bounds__(256) void bcount_kernel(const int* __restrict__ dst,
                                                     int* __restrict__ btotal, int E) {
  __shared__ int cnt[NB];
  for (int t = threadIdx.x; t < NB; t += 256) cnt[t] = 0;
  __syncthreads();
  for (int i = blockIdx.x * 256 + threadIdx.x; i < E; i += gridDim.x * 256)
    atomicAdd(&cnt[dst[i] >> BSH], 1);
  __syncthreads();
  for (int t = threadIdx.x; t < NB; t += 256)
    if (cnt[t]) atomicAdd(&btotal[t], cnt[t]);
}

// ---- stage 1: scan bucket totals -> bucket_start[NB+1], init gcur
__global__ void bscan_kernel(const int* __restrict__ btotal, int* __restrict__ bstart,
                             int* __restrict__ gcur) {
  __shared__ int s[256];
  int t = threadIdx.x;
  int v = (t < NB) ? btotal[t] : 0;
  s[t] = v;
  __syncthreads();
  for (int off = 1; off < 256; off <<= 1) {
    int a = (t >= off) ? s[t - off] : 0;
    __syncthreads();
    s[t] += a;
    __syncthreads();
  }
  int excl = s[t] - v;
  if (t < NB) { bstart[t] = excl; gcur[t] = excl; }
  if (t == NB - 1) bstart[NB] = s[t];
}

// ---- stage 2: scatter packed {src | dst_local<<17} into bucket-grouped scratch
__global__ __launch_bounds__(256) void bscatter_kernel(const int* __restrict__ src,
                                                       const int* __restrict__ dst,
                                                       int* __restrict__ gcur,
                                                       unsigned int* __restrict__ scratch, int E) {
  __shared__ int cnt[NB];
  __shared__ int base[NB];
  for (int t = threadIdx.x; t < NB; t += 256) cnt[t] = 0;
  __syncthreads();
  const int i0 = blockIdx.x * 4096;
  unsigned int v_[16];
  int b_[16], r_[16];
#pragma unroll
  for (int j = 0; j < 16; ++j) {
    int i = i0 + j * 256 + threadIdx.x;
    b_[j] = -1;
    if (i < E) {
      int d = dst[i];
      int s = src[i];
      int b = d >> BSH;
      b_[j] = b;
      r_[j] = atomicAdd(&cnt[b], 1);
      v_[j] = (unsigned int)s | ((unsigned int)(d & 511) << 17);
    }
  }
  __syncthreads();
  for (int t = threadIdx.x; t < NB; t += 256)
    base[t] = cnt[t] ? atomicAdd(&gcur[t], cnt[t]) : 0;
  __syncthreads();
#pragma unroll
  for (int j = 0; j < 16; ++j)
    if (b_[j] >= 0) scratch[base[b_[j]] + r_[j]] = v_[j];
}

// ---- stage 3: per-bucket LDS counting sort -> ssrc (dst-sorted) + offs
__global__ __launch_bounds__(512) void bsort_kernel(const unsigned int* __restrict__ scratch,
                                                    const int* __restrict__ bstart,
                                                    int* __restrict__ offs, int* __restrict__ ssrc) {
  __shared__ unsigned int buf[CAP];
  __shared__ int cnt[512], scn[512], cur[512];
  int b = blockIdx.x, t = threadIdx.x;
  int s = bstart[b], e = bstart[b + 1], n = e - s;
  int d0 = b << BSH;
  int ndst = NNODE - d0;
  if (ndst > 512) ndst = 512;
  cnt[t] = 0;
  cur[t] = 0;
  __syncthreads();
  bool fit = (n <= CAP);
  if (fit) {
    for (int i = t; i < n; i += 512) {
      unsigned int v = scratch[s + i];
      buf[i] = v;
      atomicAdd(&cnt[v >> 17], 1);
    }
  } else {
    for (int i = t; i < n; i += 512) atomicAdd(&cnt[scratch[s + i] >> 17], 1);
  }
  __syncthreads();
  scn[t] = cnt[t];
  __syncthreads();
  for (int off = 1; off < 512; off <<= 1) {
    int a = (t >= off) ? scn[t - off] : 0;
    __syncthreads();
    scn[t] += a;
    __syncthreads();
  }
  int start = scn[t] - cnt[t];  // exclusive prefix
  if (t < ndst) offs[d0 + t] = s + start;
  if (b == NB - 1 && t == 0) offs[NNODE] = e;
  __syncthreads();
  cnt[t] = start;  // repurpose: cnt[dl] = exclusive start
  __syncthreads();
  if (fit) {
    for (int i = t; i < n; i += 512) {
      unsigned int v = buf[i];
      int dl = v >> 17;
      int r = atomicAdd(&cur[dl], 1);
      ssrc[s + cnt[dl] + r] = (int)(v & 0x1FFFFu);
    }
  } else {
    for (int i = t; i < n; i += 512) {
      unsigned int v = scratch[s + i];
      int dl = v >> 17;
      int r = atomicAdd(&cur[dl], 1);
      ssrc[s + cnt[dl] + r] = (int)(v & 0x1FFFFu);
    }
  }
}

// ---- GAT aggregation: one wave per dst node; no max-subtraction (logits are tiny);
// softmax weights precomputed per-lane, (w,src) pairs via LDS broadcast reads.
__global__ __launch_bounds__(256) void aggregate_kernel(
    const __hip_bfloat16* __restrict__ z, const float* __restrict__ el,
    const float* __restrict__ er, const int* __restrict__ offs, const int* __restrict__ ssrc,
    const float* __restrict__ gat_bias, __hip_bfloat16* __restrict__ h) {
  __shared__ __align__(16) float2 ew[4][128];
  int wv = threadIdx.x >> 6, lane = threadIdx.x & 63;
  int d = blockIdx.x * 4 + wv;
  int s0 = offs[d], s1 = offs[d + 1];
  int deg = s1 - s0;
  float erd = er[d];
  const ushort2* zb2 = (const ushort2*)z;
  float acc0 = 0.f, acc1 = 0.f, ssum;
  if (deg <= 128) {
    float w0 = 0.f, w1 = 0.f;
    int src0 = 0, src1 = 0;
    if (lane < deg) { src0 = ssrc[s0 + lane]; w0 = __expf(leaky02(el[src0] + erd)); }
    if (64 + lane < deg) { src1 = ssrc[s0 + 64 + lane]; w1 = __expf(leaky02(el[src1] + erd)); }
    ssum = w0 + w1;
#pragma unroll
    for (int mm = 32; mm; mm >>= 1) ssum += __shfl_xor(ssum, mm, 64);
    ew[wv][lane] = make_float2(w0, __int_as_float(src0));
    ew[wv][64 + lane] = make_float2(w1, __int_as_float(src1));
    __builtin_amdgcn_wave_barrier();
    int i = 0;
    for (; i + 4 <= deg; i += 4) {
      float4 pA = *(const float4*)&ew[wv][i];
      float4 pB = *(const float4*)&ew[wv][i + 2];
      unsigned int oA = ((unsigned int)__float_as_uint(pA.y) << 6) + lane;
      unsigned int oB = ((unsigned int)__float_as_uint(pA.w) << 6) + lane;
      unsigned int oC = ((unsigned int)__float_as_uint(pB.y) << 6) + lane;
      unsigned int oD = ((unsigned int)__float_as_uint(pB.w) << 6) + lane;
      ushort2 vA = zb2[oA];
      ushort2 vB = zb2[oB];
      ushort2 vC = zb2[oC];
      ushort2 vD = zb2[oD];
      acc0 = fmaf(pA.x, bf2f(vA.x), acc0); acc1 = fmaf(pA.x, bf2f(vA.y), acc1);
      acc0 = fmaf(pA.z, bf2f(vB.x), acc0); acc1 = fmaf(pA.z, bf2f(vB.y), acc1);
      acc0 = fmaf(pB.x, bf2f(vC.x), acc0); acc1 = fmaf(pB.x, bf2f(vC.y), acc1);
      acc0 = fmaf(pB.z, bf2f(vD.x), acc0); acc1 = fmaf(pB.z, bf2f(vD.y), acc1);
    }
    for (; i < deg; ++i) {
      float2 p = ew[wv][i];
      unsigned int o = ((unsigned int)__float_as_uint(p.y) << 6) + lane;
      ushort2 v = zb2[o];
      acc0 = fmaf(p.x, bf2f(v.x), acc0);
      acc1 = fmaf(p.x, bf2f(v.y), acc1);
    }
  } else {
    ssum = 0.f;
    for (int i = s0; i < s1; ++i) {
      int s = ssrc[i];
      float w = __expf(leaky02(el[s] + erd));
      ssum += w;
      ushort2 cur = zb2[((unsigned int)s << 6) + lane];
      acc0 = fmaf(w, bf2f(cur.x), acc0);
      acc1 = fmaf(w, bf2f(cur.y), acc1);
    }
  }
  float inv = 1.f / ssum;
  float o0 = acc0 * inv + gat_bias[lane * 2];
  float o1 = acc1 * inv + gat_bias[lane * 2 + 1];
  o0 = (o0 > 0.f) ? o0 : (__expf(o0) - 1.f);
  o1 = (o1 > 0.f) ? o1 : (__expf(o1) - 1.f);
  ushort2 ov;
  ov.x = (unsigned short)f2bs(o0);
  ov.y = (unsigned short)f2bs(o1);
  *(ushort2*)((unsigned short*)h + (size_t)d * 128 + lane * 2) = ov;
}

// ---- link scores -> log_sigmoid, store l, track max (ordered-uint atomicMax)
__global__ __launch_bounds__(256) void score_kernel(const __hip_bfloat16* __restrict__ h,
                                                    const int* __restrict__ sa,
                                                    const int* __restrict__ sb,
                                                    float* __restrict__ lout,
                                                    unsigned int* __restrict__ maxacc, int P) {
  __shared__ float wmax[4];
  int lane = threadIdx.x & 63, wv = threadIdx.x >> 6;
  const ushort2* h2 = (const ushort2*)h;
  float lmax = -1e30f;
  for (int i = blockIdx.x * 4 + wv; i < P; i += gridDim.x * 4) {
    int a = sa[i], b = sb[i];
    ushort2 va = h2[((unsigned int)a << 6) + lane];
    ushort2 vb = h2[((unsigned int)b << 6) + lane];
    float s = bf2f(va.x) * bf2f(vb.x) + bf2f(va.y) * bf2f(vb.y);
#pragma unroll
    for (int mm = 32; mm; mm >>= 1) s += __shfl_xor(s, mm, 64);
    float l = fminf(s, 0.f) - log1pf(__expf(-fabsf(s)));
    if (lane == 0) lout[i] = l;
    lmax = fmaxf(lmax, l);
  }
  if (lane == 0) wmax[wv] = lmax;
  __syncthreads();
  if (threadIdx.x == 0) {
    float bm = fmaxf(fmaxf(wmax[0], wmax[1]), fmaxf(wmax[2], wmax[3]));
    atomicMax(maxacc, ord_of(bm));
  }
}

// ---- thresholded sum: sum of l where !(l > hold), hold = k_T * max(l)
__global__ __launch_bounds__(256) void loss_sum_kernel(const float* __restrict__ l,
                                                       const unsigned int* __restrict__ maxacc,
                                                       const int* __restrict__ alpha, int which,
                                                       float* __restrict__ sums, int P) {
  __shared__ float sdata[256];
  float a = (float)alpha[0];
  float kT = (0.5f <= a) ? 0.5f : a;
  float hold = kT * inv_ord(maxacc[which]);
  float s = 0.f;
  for (int i = blockIdx.x * 256 + threadIdx.x; i < P; i += gridDim.x * 256) {
    float v = l[i];
    if (!(v > hold)) s += v;
  }
  sdata[threadIdx.x] = s;
  __syncthreads();
  for (int off = 128; off; off >>= 1) {
    if (threadIdx.x < off) sdata[threadIdx.x] += sdata[threadIdx.x + off];
    __syncthreads();
  }
  if (threadIdx.x == 0) atomicAdd(&sums[which], sdata[0]);
}

__global__ void final_kernel(const float* __restrict__ sums, float* __restrict__ out) {
  out[0] = -(sums[0] + sums[1]);
}

extern "C" void kernel_launch(void* const* d_in, const int* in_sizes, int n_in,
                              void* d_out, int out_size, void* d_ws, size_t ws_size,
                              hipStream_t stream) {
  const float* feat_user = (const float*)d_in[0];
  const float* feat_item = (const float*)d_in[1];
  const float* W_user = (const float*)d_in[2];
  const float* b_user = (const float*)d_in[3];
  const float* W_item = (const float*)d_in[4];
  const float* b_item = (const float*)d_in[5];
  const float* W_gat = (const float*)d_in[6];
  const float* attn_l = (const float*)d_in[7];
  const float* attn_r = (const float*)d_in[8];
  const float* gat_bias = (const float*)d_in[9];
  const float* W_pred = (const float*)d_in[10];
  const float* b_pred = (const float*)d_in[11];
  const int* src = (const int*)d_in[12];
  const int* dst = (const int*)d_in[13];
  const int* pos_src = (const int*)d_in[14];
  const int* pos_dst = (const int*)d_in[15];
  const int* neg_src = (const int*)d_in[16];
  const int* neg_dst = (const int*)d_in[17];
  const int* alpha = (const int*)d_in[18];
  const int E = in_sizes[12];
  const int P = in_sizes[14];

  char* p = (char*)d_ws;
  auto alloc = [&](size_t bytes) {
    char* r = p;
    p += (bytes + 255) & ~(size_t)255;
    return r;
  };
  __hip_bfloat16* z = (__hip_bfloat16*)alloc((size_t)NNODE * 128 * 2);
  __hip_bfloat16* h = (__hip_bfloat16*)alloc((size_t)NNODE * 128 * 2);
  float* el = (float*)alloc((size_t)NNODE * 4);
  float* er = (float*)alloc((size_t)NNODE * 4);
  float* Wf_u = (float*)alloc(256 * 128 * 4);
  float* bf_u = (float*)alloc(128 * 4);
  float* Wf_i = (float*)alloc(128 * 128 * 4);
  float* bf_i = (float*)alloc(128 * 4);
  __hip_bfloat16* Bp_u = (__hip_bfloat16*)alloc(256 * 128 * 2);
  __hip_bfloat16* Bp_i = (__hip_bfloat16*)alloc(128 * 128 * 2);
  __hip_bfloat16* Bp_p = (__hip_bfloat16*)alloc(128 * 64 * 2);
  int* offs = (int*)alloc((size_t)(NNODE + 4) * 4);
  int* ssrc = (int*)alloc((size_t)E * 4);
  unsigned int* scratch = (unsigned int*)alloc((size_t)E * 4);
  float* l_pos = (float*)alloc((size_t)P * 4);
  float* l_neg = (float*)alloc((size_t)P * 4);
  int* bstart = (int*)alloc((NB + 1) * 4);
  int* gcur = (int*)alloc(NB * 4);
  // zero region: btotal[NB] | maxacc[2] | sums[2]
  int* btotal = (int*)alloc((NB + 8) * 4);
  unsigned int* maxacc = (unsigned int*)(btotal + NB);
  float* sums = (float*)(maxacc + 2);

  float* out_loss = (float*)d_out;
  float* out_pred = out_loss + 1;

  hipMemsetAsync(btotal, 0, (NB + 8) * 4, stream);

  // weight fusion + fragment packing
  fusew_kernel<<<257, 128, 0, stream>>>(W_user, b_user, W_gat, Wf_u, bf_u, 256);
  fusew_kernel<<<129, 128, 0, stream>>>(W_item, b_item, W_gat, Wf_i, bf_i, 128);
  packb_kernel<<<(256 * 128 + 255) / 256, 256, 0, stream>>>(Wf_u, Bp_u, 256, 128);
  packb_kernel<<<(128 * 128 + 255) / 256, 256, 0, stream>>>(Wf_i, Bp_i, 128, 128);
  packb_kernel<<<(128 * 64 + 255) / 256, 256, 0, stream>>>(W_pred, Bp_p, 128, 64);

  // CSR by dst via two-level bucket sort (no global random atomics)
  bcount_kernel<<<512, 256, 0, stream>>>(dst, btotal, E);
  bscan_kernel<<<1, 256, 0, stream>>>(btotal, bstart, gcur);
  bscatter_kernel<<<(E + 4095) / 4096, 256, 0, stream>>>(src, dst, gcur, scratch, E);
  bsort_kernel<<<NB, 512, 0, stream>>>(scratch, bstart, offs, ssrc);

  // z = feat @ Wf + bf (bf16 MFMA, fused el/er epilogue)
  zgemm_kernel<256><<<(NUSER + 63) / 64, 256, 0, stream>>>(feat_user, Bp_u, bf_u, attn_l, attn_r,
                                                           z, el, er, NUSER);
  zgemm_kernel<128><<<(NITEM + 63) / 64, 256, 0, stream>>>(feat_item, Bp_i, bf_i, attn_l, attn_r,
                                                           z + (size_t)NUSER * 128, el + NUSER,
                                                           er + NUSER, NITEM);

  // GAT edge-softmax aggregation -> h (bf16)
  aggregate_kernel<<<NNODE / 4, 256, 0, stream>>>(z, el, er, offs, ssrc, gat_bias, h);

  // link scores + loss
  score_kernel<<<2048, 256, 0, stream>>>(h, pos_src, pos_dst, l_pos, maxacc + 0, P);
  score_kernel<<<2048, 256, 0, stream>>>(h, neg_src, neg_dst, l_neg, maxacc + 1, P);
  loss_sum_kernel<<<512, 256, 0, stream>>>(l_pos, maxacc, alpha, 0, sums, P);
  loss_sum_kernel<<<512, 256, 0, stream>>>(l_neg, maxacc, alpha, 1, sums, P);
  final_kernel<<<1, 1, 0, stream>>>(sums, out_loss);

  // prediction head: out = h[:NUSER] @ W_pred + b_pred (bf16 MFMA)
  predgemm_kernel<<<(NUSER + 63) / 64, 256, 0, stream>>>(h, Bp_p, b_pred, out_pred, NUSER);

  (void)n_in; (void)out_size; (void)ws_size;
}

// Round 5
// 292.821 us; speedup vs baseline: 3.3215x; 1.1624x over previous
//
#include <hip/hip_runtime.h>
#include <hip/hip_bf16.h>
#include <math.h>

#define NUSER 60000
#define NITEM 60000
#define NNODE 120000
#define BSH 9
#define NB 235           // ceil(NNODE / 512)
#define CAP 8192         // per-bucket LDS capacity (mean ~6.9k, sigma ~83)

typedef __attribute__((ext_vector_type(8))) short bf16x8;
typedef __attribute__((ext_vector_type(4))) float f32x4;
typedef __attribute__((ext_vector_type(2))) float f32x2;
typedef __attribute__((ext_vector_type(8))) unsigned short u16x8;
typedef __attribute__((ext_vector_type(4))) unsigned short u16x4;

__device__ __forceinline__ float leaky02(float x) { return x > 0.f ? x : 0.2f * x; }

__device__ __forceinline__ float inv_ord(unsigned int u) {
  unsigned int bits = (u & 0x80000000u) ? (u & 0x7FFFFFFFu) : ~u;
  return __uint_as_float(bits);
}
__device__ __forceinline__ unsigned int ord_of(float f) {
  unsigned int u = __float_as_uint(f);
  return (u & 0x80000000u) ? ~u : (u | 0x80000000u);
}
__device__ __forceinline__ short f2bs(float f) {
  __hip_bfloat16 h = __float2bfloat16(f);
  return *reinterpret_cast<short*>(&h);
}

// acc += w * unpack2(bf16 pair u)   -> should lower to v_pk_fma_f32
__device__ __forceinline__ void bfma2(f32x2& acc, float w, unsigned int u) {
  f32x2 zz, ww;
  zz.x = __uint_as_float(u << 16);
  zz.y = __uint_as_float(u & 0xFFFF0000u);
  ww.x = w; ww.y = w;
  acc = __builtin_elementwise_fma(ww, zz, acc);
}
// acc += unpack2(ua) * unpack2(ub)
__device__ __forceinline__ void bprod2(f32x2& acc, unsigned int ua, unsigned int ub) {
  f32x2 a, b;
  a.x = __uint_as_float(ua << 16);
  a.y = __uint_as_float(ua & 0xFFFF0000u);
  b.x = __uint_as_float(ub << 16);
  b.y = __uint_as_float(ub & 0xFFFF0000u);
  acc = __builtin_elementwise_fma(a, b, acc);
}

// ---- fused weights: Wf[r][n] = sum_j Wa[r][j] * Wg[j][n];  bf[n] = sum_j ba[j] * Wg[j][n]
__global__ void fusew_kernel(const float* __restrict__ Wa, const float* __restrict__ ba,
                             const float* __restrict__ Wg, float* __restrict__ Wf,
                             float* __restrict__ bf, int K) {
  int n = threadIdx.x;
  int r = blockIdx.x;
  if (r < K) {
    float acc = 0.f;
#pragma unroll 8
    for (int j = 0; j < 128; ++j) acc = fmaf(Wa[r * 128 + j], Wg[j * 128 + n], acc);
    Wf[r * 128 + n] = acc;
  } else {
    float acc = 0.f;
    for (int j = 0; j < 128; ++j) acc = fmaf(ba[j], Wg[j * 128 + n], acc);
    bf[n] = acc;
  }
}

// ---- pack W (fp32 [K][N]) into MFMA B-fragment layout, bf16.
__global__ void packb_kernel(const float* __restrict__ W, __hip_bfloat16* __restrict__ Bp,
                             int K, int N) {
  int t = blockIdx.x * 256 + threadIdx.x;
  if (t >= K * N) return;
  int j = t & 7;
  int lane = (t >> 3) & 63;
  int rest = t >> 9;
  int NT = N >> 4;
  int nt = rest % NT;
  int ks = rest / NT;
  int k = ks * 32 + ((lane >> 4) << 3) + j;
  int n = nt * 16 + (lane & 15);
  Bp[t] = __float2bfloat16(W[k * N + n]);
}

// ---- z GEMM with LDS-staged A (coalesced fp32 reads -> bf16 swizzled LDS) + fused el/er.
template <int K>
__global__ __launch_bounds__(256) void zgemm_kernel(
    const float* __restrict__ A, const __hip_bfloat16* __restrict__ Bp,
    const float* __restrict__ bias, const float* __restrict__ al, const float* __restrict__ ar,
    __hip_bfloat16* __restrict__ z, float* __restrict__ el, float* __restrict__ er, int M) {
  __shared__ __align__(16) char smem[64 * 140 * 4];
  float(*lds)[140] = (float(*)[140])smem;
  const int lane = threadIdx.x & 63, wv = threadIdx.x >> 6;
  const int t = threadIdx.x;
  const int C4 = K / 4;
  for (int f = t; f < 64 * C4; f += 256) {
    int row = f / C4, c4 = f - row * C4;
    int grow = blockIdx.x * 64 + row;
    if (grow >= M) grow = M - 1;
    float4 a = *(const float4*)(A + (size_t)grow * K + c4 * 4);
    u16x4 pk;
    pk[0] = (unsigned short)f2bs(a.x);
    pk[1] = (unsigned short)f2bs(a.y);
    pk[2] = (unsigned short)f2bs(a.z);
    pk[3] = (unsigned short)f2bs(a.w);
    unsigned int byte = (unsigned int)row * (K * 2) + (unsigned int)c4 * 8;
    byte ^= (row & 7) << 4;
    *(u16x4*)(smem + byte) = pk;
  }
  __syncthreads();
  const bf16x8* bp = (const bf16x8*)Bp;
  const int frow = wv * 16 + (lane & 15);
  f32x4 acc[8] = {};
#pragma unroll
  for (int ks = 0; ks < K / 32; ++ks) {
    unsigned int byte = (unsigned int)frow * (K * 2) + (unsigned int)(ks * 32 + ((lane >> 4) << 3)) * 2;
    byte ^= (frow & 7) << 4;
    bf16x8 af = *(const bf16x8*)(smem + byte);
#pragma unroll
    for (int nt = 0; nt < 8; ++nt) {
      bf16x8 bfr = bp[(ks * 8 + nt) * 64 + lane];
      acc[nt] = __builtin_amdgcn_mfma_f32_16x16x32_bf16(af, bfr, acc[nt], 0, 0, 0);
    }
  }
  __syncthreads();
#pragma unroll
  for (int nt = 0; nt < 8; ++nt) {
    float b = bias[nt * 16 + (lane & 15)];
#pragma unroll
    for (int r = 0; r < 4; ++r)
      lds[wv * 16 + (lane >> 4) * 4 + r][nt * 16 + (lane & 15)] = acc[nt][r] + b;
  }
  __syncthreads();
  int row = threadIdx.x >> 2;
  int q = threadIdx.x & 3;
  int gm = blockIdx.x * 64 + row;
  float pl = 0.f, pr = 0.f;
  if (gm < M) {
    const float* lrow = &lds[row][q * 32];
#pragma unroll
    for (int v4 = 0; v4 < 4; ++v4) {
      u16x8 outv;
#pragma unroll
      for (int j = 0; j < 8; ++j) {
        float f = lrow[v4 * 8 + j];
        int c = q * 32 + v4 * 8 + j;
        pl = fmaf(f, al[c], pl);
        pr = fmaf(f, ar[c], pr);
        outv[j] = (unsigned short)f2bs(f);
      }
      *(u16x8*)((unsigned short*)z + (size_t)gm * 128 + q * 32 + v4 * 8) = outv;
    }
  }
  pl += __shfl_xor(pl, 1, 64); pl += __shfl_xor(pl, 2, 64);
  pr += __shfl_xor(pr, 1, 64); pr += __shfl_xor(pr, 2, 64);
  if (q == 0 && gm < M) { el[gm] = pl; er[gm] = pr; }
}

// ---- pred GEMM: out[M][64] (fp32) = h[M][128] (bf16) @ Bp(W_pred packed) + b_pred
__global__ __launch_bounds__(256) void predgemm_kernel(
    const __hip_bfloat16* __restrict__ h, const __hip_bfloat16* __restrict__ Bp,
    const float* __restrict__ bias, float* __restrict__ out, int M) {
  const int lane = threadIdx.x & 63, wv = threadIdx.x >> 6;
  const int m0 = blockIdx.x * 64 + wv * 16;
  int arow = m0 + (lane & 15);
  if (arow >= M) arow = M - 1;
  const bf16x8* a0 = (const bf16x8*)(h + (size_t)arow * 128) + (lane >> 4);
  const bf16x8* bp = (const bf16x8*)Bp;
  f32x4 acc[4] = {};
#pragma unroll
  for (int ks = 0; ks < 4; ++ks) {
    bf16x8 af = a0[ks * 4];
#pragma unroll
    for (int nt = 0; nt < 4; ++nt) {
      bf16x8 bfr = bp[(ks * 4 + nt) * 64 + lane];
      acc[nt] = __builtin_amdgcn_mfma_f32_16x16x32_bf16(af, bfr, acc[nt], 0, 0, 0);
    }
  }
#pragma unroll
  for (int nt = 0; nt < 4; ++nt) {
    int col = nt * 16 + (lane & 15);
    float b = bias[col];
#pragma unroll
    for (int r = 0; r < 4; ++r) {
      int m = m0 + (lane >> 4) * 4 + r;
      if (m < M) out[(size_t)m * 64 + col] = acc[nt][r] + b;
    }
  }
}

// ---- CSR build, stage 0: bucket counts
__global__ __launch_bounds__(256) void bcount_kernel(const int* __restrict__ dst,
                                                     int* __restrict__ btotal, int E) {
  __shared__ int cnt[NB];
  for (int t = threadIdx.x; t < NB; t += 256) cnt[t] = 0;
  __syncthreads();
  for (int i = blockIdx.x * 256 + threadIdx.x; i < E; i += gridDim.x * 256)
    atomicAdd(&cnt[dst[i] >> BSH], 1);
  __syncthreads();
  for (int t = threadIdx.x; t < NB; t += 256)
    if (cnt[t]) atomicAdd(&btotal[t], cnt[t]);
}

// ---- stage 1: scan bucket totals -> bucket_start[NB+1], init gcur
__global__ void bscan_kernel(const int* __restrict__ btotal, int* __restrict__ bstart,
                             int* __restrict__ gcur) {
  __shared__ int s[256];
  int t = threadIdx.x;
  int v = (t < NB) ? btotal[t] : 0;
  s[t] = v;
  __syncthreads();
  for (int off = 1; off < 256; off <<= 1) {
    int a = (t >= off) ? s[t - off] : 0;
    __syncthreads();
    s[t] += a;
    __syncthreads();
  }
  int excl = s[t] - v;
  if (t < NB) { bstart[t] = excl; gcur[t] = excl; }
  if (t == NB - 1) bstart[NB] = s[t];
}

// ---- stage 2: scatter packed {src | dst_local<<17} into bucket-grouped scratch
__global__ __launch_bounds__(256) void bscatter_kernel(const int* __restrict__ src,
                                                       const int* __restrict__ dst,
                                                       int* __restrict__ gcur,
                                                       unsigned int* __restrict__ scratch, int E) {
  __shared__ int cnt[NB];
  __shared__ int base[NB];
  for (int t = threadIdx.x; t < NB; t += 256) cnt[t] = 0;
  __syncthreads();
  const int i0 = blockIdx.x * 4096;
  unsigned int v_[16];
  int b_[16], r_[16];
#pragma unroll
  for (int j = 0; j < 16; ++j) {
    int i = i0 + j * 256 + threadIdx.x;
    b_[j] = -1;
    if (i < E) {
      int d = dst[i];
      int s = src[i];
      int b = d >> BSH;
      b_[j] = b;
      r_[j] = atomicAdd(&cnt[b], 1);
      v_[j] = (unsigned int)s | ((unsigned int)(d & 511) << 17);
    }
  }
  __syncthreads();
  for (int t = threadIdx.x; t < NB; t += 256)
    base[t] = cnt[t] ? atomicAdd(&gcur[t], cnt[t]) : 0;
  __syncthreads();
#pragma unroll
  for (int j = 0; j < 16; ++j)
    if (b_[j] >= 0) scratch[base[b_[j]] + r_[j]] = v_[j];
}

// ---- stage 3: per-bucket LDS counting sort -> ssrc (dst-sorted) + offs
__global__ __launch_bounds__(512) void bsort_kernel(const unsigned int* __restrict__ scratch,
                                                    const int* __restrict__ bstart,
                                                    int* __restrict__ offs, int* __restrict__ ssrc) {
  __shared__ unsigned int buf[CAP];
  __shared__ int cnt[512], scn[512], cur[512];
  int b = blockIdx.x, t = threadIdx.x;
  int s = bstart[b], e = bstart[b + 1], n = e - s;
  int d0 = b << BSH;
  int ndst = NNODE - d0;
  if (ndst > 512) ndst = 512;
  cnt[t] = 0;
  cur[t] = 0;
  __syncthreads();
  bool fit = (n <= CAP);
  if (fit) {
    for (int i = t; i < n; i += 512) {
      unsigned int v = scratch[s + i];
      buf[i] = v;
      atomicAdd(&cnt[v >> 17], 1);
    }
  } else {
    for (int i = t; i < n; i += 512) atomicAdd(&cnt[scratch[s + i] >> 17], 1);
  }
  __syncthreads();
  scn[t] = cnt[t];
  __syncthreads();
  for (int off = 1; off < 512; off <<= 1) {
    int a = (t >= off) ? scn[t - off] : 0;
    __syncthreads();
    scn[t] += a;
    __syncthreads();
  }
  int start = scn[t] - cnt[t];
  if (t < ndst) offs[d0 + t] = s + start;
  if (b == NB - 1 && t == 0) offs[NNODE] = e;
  __syncthreads();
  cnt[t] = start;
  __syncthreads();
  if (fit) {
    for (int i = t; i < n; i += 512) {
      unsigned int v = buf[i];
      int dl = v >> 17;
      int r = atomicAdd(&cur[dl], 1);
      ssrc[s + cnt[dl] + r] = (int)(v & 0x1FFFFu);
    }
  } else {
    for (int i = t; i < n; i += 512) {
      unsigned int v = scratch[s + i];
      int dl = v >> 17;
      int r = atomicAdd(&cur[dl], 1);
      ssrc[s + cnt[dl] + r] = (int)(v & 0x1FFFFu);
    }
  }
}

// ---- GAT aggregation: one wave per dst; 8-deep gather pipeline, pk-fma, no shfl reduces.
__global__ __launch_bounds__(256) void aggregate_kernel(
    const __hip_bfloat16* __restrict__ z, const float* __restrict__ el,
    const float* __restrict__ er, const int* __restrict__ offs, const int* __restrict__ ssrc,
    const float* __restrict__ gat_bias, __hip_bfloat16* __restrict__ h) {
  __shared__ __align__(16) float2 ew[4][128];
  int wv = threadIdx.x >> 6, lane = threadIdx.x & 63;
  int d = blockIdx.x * 4 + wv;
  int s0 = offs[d], s1 = offs[d + 1];
  int deg = s1 - s0;
  float erd = er[d];
  const unsigned int* zw = (const unsigned int*)z;
  f32x2 acc = {0.f, 0.f};
  float ssum = 0.f;
  if (deg <= 128) {
    float w0 = 0.f, w1 = 0.f;
    int o0 = 0, o1 = 0;
    if (lane < deg) { int s = ssrc[s0 + lane]; o0 = s << 6; w0 = __expf(leaky02(el[s] + erd)); }
    if (64 + lane < deg) { int s = ssrc[s0 + 64 + lane]; o1 = s << 6; w1 = __expf(leaky02(el[s] + erd)); }
    ew[wv][lane] = make_float2(w0, __int_as_float(o0));
    ew[wv][64 + lane] = make_float2(w1, __int_as_float(o1));
    __builtin_amdgcn_wave_barrier();
    int i = 0;
    for (; i + 8 <= deg; i += 8) {
      float4 p0 = *(const float4*)&ew[wv][i];
      float4 p1 = *(const float4*)&ew[wv][i + 2];
      float4 p2 = *(const float4*)&ew[wv][i + 4];
      float4 p3 = *(const float4*)&ew[wv][i + 6];
      unsigned int u0 = zw[__float_as_uint(p0.y) + lane];
      unsigned int u1 = zw[__float_as_uint(p0.w) + lane];
      unsigned int u2 = zw[__float_as_uint(p1.y) + lane];
      unsigned int u3 = zw[__float_as_uint(p1.w) + lane];
      unsigned int u4 = zw[__float_as_uint(p2.y) + lane];
      unsigned int u5 = zw[__float_as_uint(p2.w) + lane];
      unsigned int u6 = zw[__float_as_uint(p3.y) + lane];
      unsigned int u7 = zw[__float_as_uint(p3.w) + lane];
      ssum += ((p0.x + p0.z) + (p1.x + p1.z)) + ((p2.x + p2.z) + (p3.x + p3.z));
      bfma2(acc, p0.x, u0); bfma2(acc, p0.z, u1);
      bfma2(acc, p1.x, u2); bfma2(acc, p1.z, u3);
      bfma2(acc, p2.x, u4); bfma2(acc, p2.z, u5);
      bfma2(acc, p3.x, u6); bfma2(acc, p3.z, u7);
    }
    for (; i + 2 <= deg; i += 2) {
      float4 p = *(const float4*)&ew[wv][i];
      unsigned int ua = zw[__float_as_uint(p.y) + lane];
      unsigned int ub = zw[__float_as_uint(p.w) + lane];
      ssum += p.x + p.z;
      bfma2(acc, p.x, ua); bfma2(acc, p.z, ub);
    }
    if (i < deg) {
      float2 pp = ew[wv][i];
      unsigned int u = zw[__float_as_uint(pp.y) + lane];
      ssum += pp.x;
      bfma2(acc, pp.x, u);
    }
  } else {
    for (int i2 = s0; i2 < s1; ++i2) {
      int s = ssrc[i2];
      float w = __expf(leaky02(el[s] + erd));
      ssum += w;
      unsigned int u = zw[((unsigned int)s << 6) + lane];
      bfma2(acc, w, u);
    }
  }
  float inv = 1.f / ssum;
  float o0f = acc.x * inv + gat_bias[lane * 2];
  float o1f = acc.y * inv + gat_bias[lane * 2 + 1];
  o0f = (o0f > 0.f) ? o0f : (__expf(o0f) - 1.f);
  o1f = (o1f > 0.f) ? o1f : (__expf(o1f) - 1.f);
  ushort2 ov;
  ov.x = (unsigned short)((unsigned int)f2bs(o0f) & 0xFFFFu);
  ov.y = (unsigned short)((unsigned int)f2bs(o1f) & 0xFFFFu);
  *(ushort2*)((unsigned short*)h + (size_t)d * 128 + lane * 2) = ov;
}

// ---- link scores: 16-lane groups, 4 scores/wave, pos+neg in one launch.
__global__ __launch_bounds__(256) void score_kernel(
    const __hip_bfloat16* __restrict__ h, const int* __restrict__ ps, const int* __restrict__ pd,
    const int* __restrict__ ns, const int* __restrict__ nd, float* __restrict__ l_pos,
    float* __restrict__ l_neg, unsigned int* __restrict__ maxacc, int P) {
  const int g16 = threadIdx.x >> 4, l16 = threadIdx.x & 15;
  const uint4* h4 = (const uint4*)h;  // 16 uint4 per row
  float mpos = -1e30f, mneg = -1e30f;
  const int stride = gridDim.x * 16;
  const int tot = 2 * P;
  int i = blockIdx.x * 16 + g16;
  int a = 0, bb = 0;
  bool neg = false;
  if (i < tot) {
    neg = i >= P;
    int j = neg ? i - P : i;
    a = neg ? ns[j] : ps[j];
    bb = neg ? nd[j] : pd[j];
  }
  while (i < tot) {
    int in = i + stride;
    int an = 0, bn = 0;
    bool negn = false;
    if (in < tot) {
      negn = in >= P;
      int jn = negn ? in - P : in;
      an = negn ? ns[jn] : ps[jn];
      bn = negn ? nd[jn] : pd[jn];
    }
    uint4 va = h4[(size_t)a * 16 + l16];
    uint4 vb = h4[(size_t)bb * 16 + l16];
    f32x2 acc = {0.f, 0.f};
    bprod2(acc, va.x, vb.x);
    bprod2(acc, va.y, vb.y);
    bprod2(acc, va.z, vb.z);
    bprod2(acc, va.w, vb.w);
    float s = acc.x + acc.y;
    s += __shfl_xor(s, 1, 16);
    s += __shfl_xor(s, 2, 16);
    s += __shfl_xor(s, 4, 16);
    s += __shfl_xor(s, 8, 16);
    float lv = fminf(s, 0.f) - log1pf(__expf(-fabsf(s)));
    int j = neg ? i - P : i;
    if (l16 == 0) (neg ? l_neg : l_pos)[j] = lv;
    if (neg) mneg = fmaxf(mneg, lv); else mpos = fmaxf(mpos, lv);
    i = in; a = an; bb = bn; neg = negn;
  }
  __shared__ float red0[256], red1[256];
  red0[threadIdx.x] = mpos;
  red1[threadIdx.x] = mneg;
  __syncthreads();
  for (int off = 128; off; off >>= 1) {
    if (threadIdx.x < off) {
      red0[threadIdx.x] = fmaxf(red0[threadIdx.x], red0[threadIdx.x + off]);
      red1[threadIdx.x] = fmaxf(red1[threadIdx.x], red1[threadIdx.x + off]);
    }
    __syncthreads();
  }
  if (threadIdx.x == 0) {
    atomicMax(maxacc + 0, ord_of(red0[0]));
    atomicMax(maxacc + 1, ord_of(red1[0]));
  }
}

// ---- thresholded sum (both sets, one launch): which = blockIdx>>9
__global__ __launch_bounds__(256) void loss_sum_kernel(const float* __restrict__ l_pos,
                                                       const float* __restrict__ l_neg,
                                                       const unsigned int* __restrict__ maxacc,
                                                       const int* __restrict__ alpha,
                                                       float* __restrict__ sums, int P) {
  __shared__ float sdata[256];
  int which = blockIdx.x >> 9;
  const float* l = which ? l_neg : l_pos;
  float a = (float)alpha[0];
  float kT = (0.5f <= a) ? 0.5f : a;
  float hold = kT * inv_ord(maxacc[which]);
  float s = 0.f;
  for (int i = (blockIdx.x & 511) * 256 + threadIdx.x; i < P; i += 512 * 256) {
    float v = l[i];
    if (!(v > hold)) s += v;
  }
  sdata[threadIdx.x] = s;
  __syncthreads();
  for (int off = 128; off; off >>= 1) {
    if (threadIdx.x < off) sdata[threadIdx.x] += sdata[threadIdx.x + off];
    __syncthreads();
  }
  if (threadIdx.x == 0) atomicAdd(&sums[which], sdata[0]);
}

__global__ void final_kernel(const float* __restrict__ sums, float* __restrict__ out) {
  out[0] = -(sums[0] + sums[1]);
}

extern "C" void kernel_launch(void* const* d_in, const int* in_sizes, int n_in,
                              void* d_out, int out_size, void* d_ws, size_t ws_size,
                              hipStream_t stream) {
  const float* feat_user = (const float*)d_in[0];
  const float* feat_item = (const float*)d_in[1];
  const float* W_user = (const float*)d_in[2];
  const float* b_user = (const float*)d_in[3];
  const float* W_item = (const float*)d_in[4];
  const float* b_item = (const float*)d_in[5];
  const float* W_gat = (const float*)d_in[6];
  const float* attn_l = (const float*)d_in[7];
  const float* attn_r = (const float*)d_in[8];
  const float* gat_bias = (const float*)d_in[9];
  const float* W_pred = (const float*)d_in[10];
  const float* b_pred = (const float*)d_in[11];
  const int* src = (const int*)d_in[12];
  const int* dst = (const int*)d_in[13];
  const int* pos_src = (const int*)d_in[14];
  const int* pos_dst = (const int*)d_in[15];
  const int* neg_src = (const int*)d_in[16];
  const int* neg_dst = (const int*)d_in[17];
  const int* alpha = (const int*)d_in[18];
  const int E = in_sizes[12];
  const int P = in_sizes[14];

  char* p = (char*)d_ws;
  auto alloc = [&](size_t bytes) {
    char* r = p;
    p += (bytes + 255) & ~(size_t)255;
    return r;
  };
  __hip_bfloat16* z = (__hip_bfloat16*)alloc((size_t)NNODE * 128 * 2);
  __hip_bfloat16* h = (__hip_bfloat16*)alloc((size_t)NNODE * 128 * 2);
  float* el = (float*)alloc((size_t)NNODE * 4);
  float* er = (float*)alloc((size_t)NNODE * 4);
  float* Wf_u = (float*)alloc(256 * 128 * 4);
  float* bf_u = (float*)alloc(128 * 4);
  float* Wf_i = (float*)alloc(128 * 128 * 4);
  float* bf_i = (float*)alloc(128 * 4);
  __hip_bfloat16* Bp_u = (__hip_bfloat16*)alloc(256 * 128 * 2);
  __hip_bfloat16* Bp_i = (__hip_bfloat16*)alloc(128 * 128 * 2);
  __hip_bfloat16* Bp_p = (__hip_bfloat16*)alloc(128 * 64 * 2);
  int* offs = (int*)alloc((size_t)(NNODE + 4) * 4);
  int* ssrc = (int*)alloc((size_t)E * 4);
  unsigned int* scratch = (unsigned int*)alloc((size_t)E * 4);
  float* l_pos = (float*)alloc((size_t)P * 4);
  float* l_neg = (float*)alloc((size_t)P * 4);
  int* bstart = (int*)alloc((NB + 1) * 4);
  int* gcur = (int*)alloc(NB * 4);
  // zero region: btotal[NB] | maxacc[2] | sums[2]
  int* btotal = (int*)alloc((NB + 8) * 4);
  unsigned int* maxacc = (unsigned int*)(btotal + NB);
  float* sums = (float*)(maxacc + 2);

  float* out_loss = (float*)d_out;
  float* out_pred = out_loss + 1;

  hipMemsetAsync(btotal, 0, (NB + 8) * 4, stream);

  // weight fusion + fragment packing
  fusew_kernel<<<257, 128, 0, stream>>>(W_user, b_user, W_gat, Wf_u, bf_u, 256);
  fusew_kernel<<<129, 128, 0, stream>>>(W_item, b_item, W_gat, Wf_i, bf_i, 128);
  packb_kernel<<<(256 * 128 + 255) / 256, 256, 0, stream>>>(Wf_u, Bp_u, 256, 128);
  packb_kernel<<<(128 * 128 + 255) / 256, 256, 0, stream>>>(Wf_i, Bp_i, 128, 128);
  packb_kernel<<<(128 * 64 + 255) / 256, 256, 0, stream>>>(W_pred, Bp_p, 128, 64);

  // CSR by dst via two-level bucket sort (no global random atomics)
  bcount_kernel<<<512, 256, 0, stream>>>(dst, btotal, E);
  bscan_kernel<<<1, 256, 0, stream>>>(btotal, bstart, gcur);
  bscatter_kernel<<<(E + 4095) / 4096, 256, 0, stream>>>(src, dst, gcur, scratch, E);
  bsort_kernel<<<NB, 512, 0, stream>>>(scratch, bstart, offs, ssrc);

  // z = feat @ Wf + bf (bf16 MFMA, fused el/er epilogue)
  zgemm_kernel<256><<<(NUSER + 63) / 64, 256, 0, stream>>>(feat_user, Bp_u, bf_u, attn_l, attn_r,
                                                           z, el, er, NUSER);
  zgemm_kernel<128><<<(NITEM + 63) / 64, 256, 0, stream>>>(feat_item, Bp_i, bf_i, attn_l, attn_r,
                                                           z + (size_t)NUSER * 128, el + NUSER,
                                                           er + NUSER, NITEM);

  // GAT edge-softmax aggregation -> h (bf16)
  aggregate_kernel<<<NNODE / 4, 256, 0, stream>>>(z, el, er, offs, ssrc, gat_bias, h);

  // link scores (pos+neg fused) + loss
  score_kernel<<<2048, 256, 0, stream>>>(h, pos_src, pos_dst, neg_src, neg_dst, l_pos, l_neg,
                                         maxacc, P);
  loss_sum_kernel<<<1024, 256, 0, stream>>>(l_pos, l_neg, maxacc, alpha, sums, P);
  final_kernel<<<1, 1, 0, stream>>>(sums, out_loss);

  // prediction head: out = h[:NUSER] @ W_pred + b_pred (bf16 MFMA)
  predgemm_kernel<<<(NUSER + 63) / 64, 256, 0, stream>>>(h, Bp_p, b_pred, out_pred, NUSER);

  (void)n_in; (void)out_size; (void)ws_size;
}

// Round 6
// 289.367 us; speedup vs baseline: 3.3611x; 1.0119x over previous
//
#include <hip/hip_runtime.h>
#include <hip/hip_bf16.h>
#include <math.h>

#define NUSER 60000
#define NITEM 60000
#define NNODE 120000
#define BSH 9
#define NB 235           // ceil(NNODE / 512)
#define CAP 8192         // per-bucket LDS capacity (mean ~6.9k, sigma ~83)

typedef __attribute__((ext_vector_type(8))) short bf16x8;
typedef __attribute__((ext_vector_type(4))) float f32x4;
typedef __attribute__((ext_vector_type(2))) float f32x2;
typedef __attribute__((ext_vector_type(8))) unsigned short u16x8;
typedef __attribute__((ext_vector_type(4))) unsigned short u16x4;

__device__ __forceinline__ float leaky02(float x) { return x > 0.f ? x : 0.2f * x; }

__device__ __forceinline__ float inv_ord(unsigned int u) {
  unsigned int bits = (u & 0x80000000u) ? (u & 0x7FFFFFFFu) : ~u;
  return __uint_as_float(bits);
}
__device__ __forceinline__ unsigned int ord_of(float f) {
  unsigned int u = __float_as_uint(f);
  return (u & 0x80000000u) ? ~u : (u | 0x80000000u);
}
__device__ __forceinline__ short f2bs(float f) {
  __hip_bfloat16 h = __float2bfloat16(f);
  return *reinterpret_cast<short*>(&h);
}

// acc += w * unpack2(bf16 pair u)   -> v_pk_fma_f32
__device__ __forceinline__ void bfma2(f32x2& acc, float w, unsigned int u) {
  f32x2 zz, ww;
  zz.x = __uint_as_float(u << 16);
  zz.y = __uint_as_float(u & 0xFFFF0000u);
  ww.x = w; ww.y = w;
  acc = __builtin_elementwise_fma(ww, zz, acc);
}
// acc += dot of 4 fp8 pairs (ua, ub are 4 packed e4m3 each)
__device__ __forceinline__ void fp8dot(f32x2& acc, unsigned int ua, unsigned int ub) {
  f32x2 a0 = __builtin_amdgcn_cvt_pk_f32_fp8(ua, false);
  f32x2 a1 = __builtin_amdgcn_cvt_pk_f32_fp8(ua, true);
  f32x2 b0 = __builtin_amdgcn_cvt_pk_f32_fp8(ub, false);
  f32x2 b1 = __builtin_amdgcn_cvt_pk_f32_fp8(ub, true);
  acc = __builtin_elementwise_fma(a0, b0, acc);
  acc = __builtin_elementwise_fma(a1, b1, acc);
}

// ---- fused weights: Wf[r][n] = sum_j Wa[r][j] * Wg[j][n];  bf[n] = sum_j ba[j] * Wg[j][n]
__global__ void fusew_kernel(const float* __restrict__ Wa, const float* __restrict__ ba,
                             const float* __restrict__ Wg, float* __restrict__ Wf,
                             float* __restrict__ bf, int K) {
  int n = threadIdx.x;
  int r = blockIdx.x;
  if (r < K) {
    float acc = 0.f;
#pragma unroll 8
    for (int j = 0; j < 128; ++j) acc = fmaf(Wa[r * 128 + j], Wg[j * 128 + n], acc);
    Wf[r * 128 + n] = acc;
  } else {
    float acc = 0.f;
    for (int j = 0; j < 128; ++j) acc = fmaf(ba[j], Wg[j * 128 + n], acc);
    bf[n] = acc;
  }
}

// ---- pack W (fp32 [K][N]) into MFMA B-fragment layout, bf16.
__global__ void packb_kernel(const float* __restrict__ W, __hip_bfloat16* __restrict__ Bp,
                             int K, int N) {
  int t = blockIdx.x * 256 + threadIdx.x;
  if (t >= K * N) return;
  int j = t & 7;
  int lane = (t >> 3) & 63;
  int rest = t >> 9;
  int NT = N >> 4;
  int nt = rest % NT;
  int ks = rest / NT;
  int k = ks * 32 + ((lane >> 4) << 3) + j;
  int n = nt * 16 + (lane & 15);
  Bp[t] = __float2bfloat16(W[k * N + n]);
}

// ---- z GEMM with LDS-staged A (coalesced fp32 reads -> bf16 swizzled LDS) + fused el/er.
template <int K>
__global__ __launch_bounds__(256) void zgemm_kernel(
    const float* __restrict__ A, const __hip_bfloat16* __restrict__ Bp,
    const float* __restrict__ bias, const float* __restrict__ al, const float* __restrict__ ar,
    __hip_bfloat16* __restrict__ z, float* __restrict__ el, float* __restrict__ er, int M) {
  __shared__ __align__(16) char smem[64 * 140 * 4];
  float(*lds)[140] = (float(*)[140])smem;
  const int lane = threadIdx.x & 63, wv = threadIdx.x >> 6;
  const int t = threadIdx.x;
  const int C4 = K / 4;
  for (int f = t; f < 64 * C4; f += 256) {
    int row = f / C4, c4 = f - row * C4;
    int grow = blockIdx.x * 64 + row;
    if (grow >= M) grow = M - 1;
    float4 a = *(const float4*)(A + (size_t)grow * K + c4 * 4);
    u16x4 pk;
    pk[0] = (unsigned short)f2bs(a.x);
    pk[1] = (unsigned short)f2bs(a.y);
    pk[2] = (unsigned short)f2bs(a.z);
    pk[3] = (unsigned short)f2bs(a.w);
    unsigned int byte = (unsigned int)row * (K * 2) + (unsigned int)c4 * 8;
    byte ^= (row & 7) << 4;
    *(u16x4*)(smem + byte) = pk;
  }
  __syncthreads();
  const bf16x8* bp = (const bf16x8*)Bp;
  const int frow = wv * 16 + (lane & 15);
  f32x4 acc[8] = {};
#pragma unroll
  for (int ks = 0; ks < K / 32; ++ks) {
    unsigned int byte = (unsigned int)frow * (K * 2) + (unsigned int)(ks * 32 + ((lane >> 4) << 3)) * 2;
    byte ^= (frow & 7) << 4;
    bf16x8 af = *(const bf16x8*)(smem + byte);
#pragma unroll
    for (int nt = 0; nt < 8; ++nt) {
      bf16x8 bfr = bp[(ks * 8 + nt) * 64 + lane];
      acc[nt] = __builtin_amdgcn_mfma_f32_16x16x32_bf16(af, bfr, acc[nt], 0, 0, 0);
    }
  }
  __syncthreads();
#pragma unroll
  for (int nt = 0; nt < 8; ++nt) {
    float b = bias[nt * 16 + (lane & 15)];
#pragma unroll
    for (int r = 0; r < 4; ++r)
      lds[wv * 16 + (lane >> 4) * 4 + r][nt * 16 + (lane & 15)] = acc[nt][r] + b;
  }
  __syncthreads();
  int row = threadIdx.x >> 2;
  int q = threadIdx.x & 3;
  int gm = blockIdx.x * 64 + row;
  float pl = 0.f, pr = 0.f;
  if (gm < M) {
    const float* lrow = &lds[row][q * 32];
#pragma unroll
    for (int v4 = 0; v4 < 4; ++v4) {
      u16x8 outv;
#pragma unroll
      for (int j = 0; j < 8; ++j) {
        float f = lrow[v4 * 8 + j];
        int c = q * 32 + v4 * 8 + j;
        pl = fmaf(f, al[c], pl);
        pr = fmaf(f, ar[c], pr);
        outv[j] = (unsigned short)f2bs(f);
      }
      *(u16x8*)((unsigned short*)z + (size_t)gm * 128 + q * 32 + v4 * 8) = outv;
    }
  }
  pl += __shfl_xor(pl, 1, 64); pl += __shfl_xor(pl, 2, 64);
  pr += __shfl_xor(pr, 1, 64); pr += __shfl_xor(pr, 2, 64);
  if (q == 0 && gm < M) { el[gm] = pl; er[gm] = pr; }
}

// ---- pred GEMM: out[M][64] (fp32) = h[M][128] (bf16) @ Bp(W_pred packed) + b_pred
__global__ __launch_bounds__(256) void predgemm_kernel(
    const __hip_bfloat16* __restrict__ h, const __hip_bfloat16* __restrict__ Bp,
    const float* __restrict__ bias, float* __restrict__ out, int M) {
  const int lane = threadIdx.x & 63, wv = threadIdx.x >> 6;
  const int m0 = blockIdx.x * 64 + wv * 16;
  int arow = m0 + (lane & 15);
  if (arow >= M) arow = M - 1;
  const bf16x8* a0 = (const bf16x8*)(h + (size_t)arow * 128) + (lane >> 4);
  const bf16x8* bp = (const bf16x8*)Bp;
  f32x4 acc[4] = {};
#pragma unroll
  for (int ks = 0; ks < 4; ++ks) {
    bf16x8 af = a0[ks * 4];
#pragma unroll
    for (int nt = 0; nt < 4; ++nt) {
      bf16x8 bfr = bp[(ks * 4 + nt) * 64 + lane];
      acc[nt] = __builtin_amdgcn_mfma_f32_16x16x32_bf16(af, bfr, acc[nt], 0, 0, 0);
    }
  }
#pragma unroll
  for (int nt = 0; nt < 4; ++nt) {
    int col = nt * 16 + (lane & 15);
    float b = bias[col];
#pragma unroll
    for (int r = 0; r < 4; ++r) {
      int m = m0 + (lane >> 4) * 4 + r;
      if (m < M) out[(size_t)m * 64 + col] = acc[nt][r] + b;
    }
  }
}

// ---- CSR build, stage 0: bucket counts
__global__ __launch_bounds__(256) void bcount_kernel(const int* __restrict__ dst,
                                                     int* __restrict__ btotal, int E) {
  __shared__ int cnt[NB];
  for (int t = threadIdx.x; t < NB; t += 256) cnt[t] = 0;
  __syncthreads();
  for (int i = blockIdx.x * 256 + threadIdx.x; i < E; i += gridDim.x * 256)
    atomicAdd(&cnt[dst[i] >> BSH], 1);
  __syncthreads();
  for (int t = threadIdx.x; t < NB; t += 256)
    if (cnt[t]) atomicAdd(&btotal[t], cnt[t]);
}

// ---- stage 1: scan bucket totals -> bucket_start[NB+1], init gcur
__global__ void bscan_kernel(const int* __restrict__ btotal, int* __restrict__ bstart,
                             int* __restrict__ gcur) {
  __shared__ int s[256];
  int t = threadIdx.x;
  int v = (t < NB) ? btotal[t] : 0;
  s[t] = v;
  __syncthreads();
  for (int off = 1; off < 256; off <<= 1) {
    int a = (t >= off) ? s[t - off] : 0;
    __syncthreads();
    s[t] += a;
    __syncthreads();
  }
  int excl = s[t] - v;
  if (t < NB) { bstart[t] = excl; gcur[t] = excl; }
  if (t == NB - 1) bstart[NB] = s[t];
}

// ---- stage 2: scatter packed {src | dst_local<<17} into bucket-grouped scratch
__global__ __launch_bounds__(256) void bscatter_kernel(const int* __restrict__ src,
                                                       const int* __restrict__ dst,
                                                       int* __restrict__ gcur,
                                                       unsigned int* __restrict__ scratch, int E) {
  __shared__ int cnt[NB];
  __shared__ int base[NB];
  for (int t = threadIdx.x; t < NB; t += 256) cnt[t] = 0;
  __syncthreads();
  const int i0 = blockIdx.x * 4096;
  unsigned int v_[16];
  int b_[16], r_[16];
#pragma unroll
  for (int j = 0; j < 16; ++j) {
    int i = i0 + j * 256 + threadIdx.x;
    b_[j] = -1;
    if (i < E) {
      int d = dst[i];
      int s = src[i];
      int b = d >> BSH;
      b_[j] = b;
      r_[j] = atomicAdd(&cnt[b], 1);
      v_[j] = (unsigned int)s | ((unsigned int)(d & 511) << 17);
    }
  }
  __syncthreads();
  for (int t = threadIdx.x; t < NB; t += 256)
    base[t] = cnt[t] ? atomicAdd(&gcur[t], cnt[t]) : 0;
  __syncthreads();
#pragma unroll
  for (int j = 0; j < 16; ++j)
    if (b_[j] >= 0) scratch[base[b_[j]] + r_[j]] = v_[j];
}

// ---- stage 3: per-bucket LDS counting sort -> ssrc (dst-sorted) + offs
__global__ __launch_bounds__(512) void bsort_kernel(const unsigned int* __restrict__ scratch,
                                                    const int* __restrict__ bstart,
                                                    int* __restrict__ offs, int* __restrict__ ssrc) {
  __shared__ unsigned int buf[CAP];
  __shared__ int cnt[512], scn[512], cur[512];
  int b = blockIdx.x, t = threadIdx.x;
  int s = bstart[b], e = bstart[b + 1], n = e - s;
  int d0 = b << BSH;
  int ndst = NNODE - d0;
  if (ndst > 512) ndst = 512;
  cnt[t] = 0;
  cur[t] = 0;
  __syncthreads();
  bool fit = (n <= CAP);
  if (fit) {
    for (int i = t; i < n; i += 512) {
      unsigned int v = scratch[s + i];
      buf[i] = v;
      atomicAdd(&cnt[v >> 17], 1);
    }
  } else {
    for (int i = t; i < n; i += 512) atomicAdd(&cnt[scratch[s + i] >> 17], 1);
  }
  __syncthreads();
  scn[t] = cnt[t];
  __syncthreads();
  for (int off = 1; off < 512; off <<= 1) {
    int a = (t >= off) ? scn[t - off] : 0;
    __syncthreads();
    scn[t] += a;
    __syncthreads();
  }
  int start = scn[t] - cnt[t];
  if (t < ndst) offs[d0 + t] = s + start;
  if (b == NB - 1 && t == 0) offs[NNODE] = e;
  __syncthreads();
  cnt[t] = start;
  __syncthreads();
  if (fit) {
    for (int i = t; i < n; i += 512) {
      unsigned int v = buf[i];
      int dl = v >> 17;
      int r = atomicAdd(&cur[dl], 1);
      ssrc[s + cnt[dl] + r] = (int)(v & 0x1FFFFu);
    }
  } else {
    for (int i = t; i < n; i += 512) {
      unsigned int v = scratch[s + i];
      int dl = v >> 17;
      int r = atomicAdd(&cur[dl], 1);
      ssrc[s + cnt[dl] + r] = (int)(v & 0x1FFFFu);
    }
  }
}

// ---- GAT aggregation: one wave per dst; 8-deep gather pipeline, pk-fma.
// Writes h (bf16, for predgemm) and h8 (fp8 e4m3, for score gathers).
__global__ __launch_bounds__(256) void aggregate_kernel(
    const __hip_bfloat16* __restrict__ z, const float* __restrict__ el,
    const float* __restrict__ er, const int* __restrict__ offs, const int* __restrict__ ssrc,
    const float* __restrict__ gat_bias, __hip_bfloat16* __restrict__ h,
    unsigned char* __restrict__ h8) {
  __shared__ __align__(16) float2 ew[4][128];
  int wv = threadIdx.x >> 6, lane = threadIdx.x & 63;
  int d = blockIdx.x * 4 + wv;
  int s0 = offs[d], s1 = offs[d + 1];
  int deg = s1 - s0;
  float erd = er[d];
  const unsigned int* zw = (const unsigned int*)z;
  f32x2 acc = {0.f, 0.f};
  float ssum = 0.f;
  if (deg <= 128) {
    float w0 = 0.f, w1 = 0.f;
    int o0 = 0, o1 = 0;
    if (lane < deg) { int s = ssrc[s0 + lane]; o0 = s << 6; w0 = __expf(leaky02(el[s] + erd)); }
    if (64 + lane < deg) { int s = ssrc[s0 + 64 + lane]; o1 = s << 6; w1 = __expf(leaky02(el[s] + erd)); }
    ew[wv][lane] = make_float2(w0, __int_as_float(o0));
    ew[wv][64 + lane] = make_float2(w1, __int_as_float(o1));
    __builtin_amdgcn_wave_barrier();
    int i = 0;
    for (; i + 8 <= deg; i += 8) {
      float4 p0 = *(const float4*)&ew[wv][i];
      float4 p1 = *(const float4*)&ew[wv][i + 2];
      float4 p2 = *(const float4*)&ew[wv][i + 4];
      float4 p3 = *(const float4*)&ew[wv][i + 6];
      unsigned int u0 = zw[__float_as_uint(p0.y) + lane];
      unsigned int u1 = zw[__float_as_uint(p0.w) + lane];
      unsigned int u2 = zw[__float_as_uint(p1.y) + lane];
      unsigned int u3 = zw[__float_as_uint(p1.w) + lane];
      unsigned int u4 = zw[__float_as_uint(p2.y) + lane];
      unsigned int u5 = zw[__float_as_uint(p2.w) + lane];
      unsigned int u6 = zw[__float_as_uint(p3.y) + lane];
      unsigned int u7 = zw[__float_as_uint(p3.w) + lane];
      ssum += ((p0.x + p0.z) + (p1.x + p1.z)) + ((p2.x + p2.z) + (p3.x + p3.z));
      bfma2(acc, p0.x, u0); bfma2(acc, p0.z, u1);
      bfma2(acc, p1.x, u2); bfma2(acc, p1.z, u3);
      bfma2(acc, p2.x, u4); bfma2(acc, p2.z, u5);
      bfma2(acc, p3.x, u6); bfma2(acc, p3.z, u7);
    }
    for (; i + 2 <= deg; i += 2) {
      float4 p = *(const float4*)&ew[wv][i];
      unsigned int ua = zw[__float_as_uint(p.y) + lane];
      unsigned int ub = zw[__float_as_uint(p.w) + lane];
      ssum += p.x + p.z;
      bfma2(acc, p.x, ua); bfma2(acc, p.z, ub);
    }
    if (i < deg) {
      float2 pp = ew[wv][i];
      unsigned int u = zw[__float_as_uint(pp.y) + lane];
      ssum += pp.x;
      bfma2(acc, pp.x, u);
    }
  } else {
    for (int i2 = s0; i2 < s1; ++i2) {
      int s = ssrc[i2];
      float w = __expf(leaky02(el[s] + erd));
      ssum += w;
      unsigned int u = zw[((unsigned int)s << 6) + lane];
      bfma2(acc, w, u);
    }
  }
  float inv = 1.f / ssum;
  float o0f = acc.x * inv + gat_bias[lane * 2];
  float o1f = acc.y * inv + gat_bias[lane * 2 + 1];
  o0f = (o0f > 0.f) ? o0f : (__expf(o0f) - 1.f);
  o1f = (o1f > 0.f) ? o1f : (__expf(o1f) - 1.f);
  ushort2 ov;
  ov.x = (unsigned short)((unsigned int)f2bs(o0f) & 0xFFFFu);
  ov.y = (unsigned short)((unsigned int)f2bs(o1f) & 0xFFFFu);
  *(ushort2*)((unsigned short*)h + (size_t)d * 128 + lane * 2) = ov;
  int pk8 = __builtin_amdgcn_cvt_pk_fp8_f32(o0f, o1f, 0, false);
  *(unsigned short*)(h8 + (size_t)d * 128 + lane * 2) = (unsigned short)(pk8 & 0xFFFF);
}

// ---- link scores from fp8 h-copy: 16-lane groups, 3-stage pipeline, pos+neg fused.
__global__ __launch_bounds__(256) void score_kernel(
    const unsigned char* __restrict__ h8, const int* __restrict__ ps, const int* __restrict__ pd,
    const int* __restrict__ ns, const int* __restrict__ nd, float* __restrict__ l_pos,
    float* __restrict__ l_neg, unsigned int* __restrict__ maxacc, int P) {
  const int g16 = threadIdx.x >> 4, l16 = threadIdx.x & 15;
  const uint2* h2 = (const uint2*)h8;  // 16 uint2 per 128B row
  const int stride = gridDim.x * 16;
  const int tot = 2 * P;
  float mpos = -1e30f, mneg = -1e30f;

  int i = blockIdx.x * 16 + g16;
  int aC = 0, bC = 0;
  if (i < tot) {
    bool n = i >= P; int j = n ? i - P : i;
    aC = n ? ns[j] : ps[j]; bC = n ? nd[j] : pd[j];
  }
  uint2 vaC = {0, 0}, vbC = {0, 0};
  if (i < tot) {
    vaC = h2[(size_t)aC * 16 + l16];
    vbC = h2[(size_t)bC * 16 + l16];
  }
  int i1 = i + stride;
  int aN = 0, bN = 0;
  if (i1 < tot) {
    bool n = i1 >= P; int j = n ? i1 - P : i1;
    aN = n ? ns[j] : ps[j]; bN = n ? nd[j] : pd[j];
  }

  while (i < tot) {
    // stage: row loads for i1
    uint2 vaN = {0, 0}, vbN = {0, 0};
    if (i1 < tot) {
      vaN = h2[(size_t)aN * 16 + l16];
      vbN = h2[(size_t)bN * 16 + l16];
    }
    // stage: index loads for i2
    int i2 = i1 + stride;
    int aN2 = 0, bN2 = 0;
    if (i2 < tot) {
      bool n = i2 >= P; int j = n ? i2 - P : i2;
      aN2 = n ? ns[j] : ps[j]; bN2 = n ? nd[j] : pd[j];
    }
    // compute current
    f32x2 acc = {0.f, 0.f};
    fp8dot(acc, vaC.x, vbC.x);
    fp8dot(acc, vaC.y, vbC.y);
    float s = acc.x + acc.y;
    s += __shfl_xor(s, 1, 16);
    s += __shfl_xor(s, 2, 16);
    s += __shfl_xor(s, 4, 16);
    s += __shfl_xor(s, 8, 16);
    float lv = fminf(s, 0.f) - log1pf(__expf(-fabsf(s)));
    bool neg = i >= P;
    int j = neg ? i - P : i;
    if (l16 == 0) (neg ? l_neg : l_pos)[j] = lv;
    if (neg) mneg = fmaxf(mneg, lv); else mpos = fmaxf(mpos, lv);
    // rotate pipeline
    i = i1; i1 = i2;
    aC = aN; bC = bN; aN = aN2; bN = bN2;
    vaC = vaN; vbC = vbN;
  }
  __shared__ float red0[256], red1[256];
  red0[threadIdx.x] = mpos;
  red1[threadIdx.x] = mneg;
  __syncthreads();
  for (int off = 128; off; off >>= 1) {
    if (threadIdx.x < off) {
      red0[threadIdx.x] = fmaxf(red0[threadIdx.x], red0[threadIdx.x + off]);
      red1[threadIdx.x] = fmaxf(red1[threadIdx.x], red1[threadIdx.x + off]);
    }
    __syncthreads();
  }
  if (threadIdx.x == 0) {
    atomicMax(maxacc + 0, ord_of(red0[0]));
    atomicMax(maxacc + 1, ord_of(red1[0]));
  }
}

// ---- thresholded sum (both sets, one launch): which = blockIdx>>9
__global__ __launch_bounds__(256) void loss_sum_kernel(const float* __restrict__ l_pos,
                                                       const float* __restrict__ l_neg,
                                                       const unsigned int* __restrict__ maxacc,
                                                       const int* __restrict__ alpha,
                                                       float* __restrict__ sums, int P) {
  __shared__ float sdata[256];
  int which = blockIdx.x >> 9;
  const float* l = which ? l_neg : l_pos;
  float a = (float)alpha[0];
  float kT = (0.5f <= a) ? 0.5f : a;
  float hold = kT * inv_ord(maxacc[which]);
  float s = 0.f;
  for (int i = (blockIdx.x & 511) * 256 + threadIdx.x; i < P; i += 512 * 256) {
    float v = l[i];
    if (!(v > hold)) s += v;
  }
  sdata[threadIdx.x] = s;
  __syncthreads();
  for (int off = 128; off; off >>= 1) {
    if (threadIdx.x < off) sdata[threadIdx.x] += sdata[threadIdx.x + off];
    __syncthreads();
  }
  if (threadIdx.x == 0) atomicAdd(&sums[which], sdata[0]);
}

__global__ void final_kernel(const float* __restrict__ sums, float* __restrict__ out) {
  out[0] = -(sums[0] + sums[1]);
}

extern "C" void kernel_launch(void* const* d_in, const int* in_sizes, int n_in,
                              void* d_out, int out_size, void* d_ws, size_t ws_size,
                              hipStream_t stream) {
  const float* feat_user = (const float*)d_in[0];
  const float* feat_item = (const float*)d_in[1];
  const float* W_user = (const float*)d_in[2];
  const float* b_user = (const float*)d_in[3];
  const float* W_item = (const float*)d_in[4];
  const float* b_item = (const float*)d_in[5];
  const float* W_gat = (const float*)d_in[6];
  const float* attn_l = (const float*)d_in[7];
  const float* attn_r = (const float*)d_in[8];
  const float* gat_bias = (const float*)d_in[9];
  const float* W_pred = (const float*)d_in[10];
  const float* b_pred = (const float*)d_in[11];
  const int* src = (const int*)d_in[12];
  const int* dst = (const int*)d_in[13];
  const int* pos_src = (const int*)d_in[14];
  const int* pos_dst = (const int*)d_in[15];
  const int* neg_src = (const int*)d_in[16];
  const int* neg_dst = (const int*)d_in[17];
  const int* alpha = (const int*)d_in[18];
  const int E = in_sizes[12];
  const int P = in_sizes[14];

  char* p = (char*)d_ws;
  auto alloc = [&](size_t bytes) {
    char* r = p;
    p += (bytes + 255) & ~(size_t)255;
    return r;
  };
  __hip_bfloat16* z = (__hip_bfloat16*)alloc((size_t)NNODE * 128 * 2);
  __hip_bfloat16* h = (__hip_bfloat16*)alloc((size_t)NNODE * 128 * 2);
  unsigned char* h8 = (unsigned char*)alloc((size_t)NNODE * 128);
  float* el = (float*)alloc((size_t)NNODE * 4);
  float* er = (float*)alloc((size_t)NNODE * 4);
  float* Wf_u = (float*)alloc(256 * 128 * 4);
  float* bf_u = (float*)alloc(128 * 4);
  float* Wf_i = (float*)alloc(128 * 128 * 4);
  float* bf_i = (float*)alloc(128 * 4);
  __hip_bfloat16* Bp_u = (__hip_bfloat16*)alloc(256 * 128 * 2);
  __hip_bfloat16* Bp_i = (__hip_bfloat16*)alloc(128 * 128 * 2);
  __hip_bfloat16* Bp_p = (__hip_bfloat16*)alloc(128 * 64 * 2);
  int* offs = (int*)alloc((size_t)(NNODE + 4) * 4);
  int* ssrc = (int*)alloc((size_t)E * 4);
  unsigned int* scratch = (unsigned int*)alloc((size_t)E * 4);
  float* l_pos = (float*)alloc((size_t)P * 4);
  float* l_neg = (float*)alloc((size_t)P * 4);
  int* bstart = (int*)alloc((NB + 1) * 4);
  int* gcur = (int*)alloc(NB * 4);
  // zero region: btotal[NB] | maxacc[2] | sums[2]
  int* btotal = (int*)alloc((NB + 8) * 4);
  unsigned int* maxacc = (unsigned int*)(btotal + NB);
  float* sums = (float*)(maxacc + 2);

  float* out_loss = (float*)d_out;
  float* out_pred = out_loss + 1;

  hipMemsetAsync(btotal, 0, (NB + 8) * 4, stream);

  // weight fusion + fragment packing
  fusew_kernel<<<257, 128, 0, stream>>>(W_user, b_user, W_gat, Wf_u, bf_u, 256);
  fusew_kernel<<<129, 128, 0, stream>>>(W_item, b_item, W_gat, Wf_i, bf_i, 128);
  packb_kernel<<<(256 * 128 + 255) / 256, 256, 0, stream>>>(Wf_u, Bp_u, 256, 128);
  packb_kernel<<<(128 * 128 + 255) / 256, 256, 0, stream>>>(Wf_i, Bp_i, 128, 128);
  packb_kernel<<<(128 * 64 + 255) / 256, 256, 0, stream>>>(W_pred, Bp_p, 128, 64);

  // CSR by dst via two-level bucket sort (no global random atomics)
  bcount_kernel<<<512, 256, 0, stream>>>(dst, btotal, E);
  bscan_kernel<<<1, 256, 0, stream>>>(btotal, bstart, gcur);
  bscatter_kernel<<<(E + 4095) / 4096, 256, 0, stream>>>(src, dst, gcur, scratch, E);
  bsort_kernel<<<NB, 512, 0, stream>>>(scratch, bstart, offs, ssrc);

  // z = feat @ Wf + bf (bf16 MFMA, fused el/er epilogue)
  zgemm_kernel<256><<<(NUSER + 63) / 64, 256, 0, stream>>>(feat_user, Bp_u, bf_u, attn_l, attn_r,
                                                           z, el, er, NUSER);
  zgemm_kernel<128><<<(NITEM + 63) / 64, 256, 0, stream>>>(feat_item, Bp_i, bf_i, attn_l, attn_r,
                                                           z + (size_t)NUSER * 128, el + NUSER,
                                                           er + NUSER, NITEM);

  // GAT edge-softmax aggregation -> h (bf16) + h8 (fp8)
  aggregate_kernel<<<NNODE / 4, 256, 0, stream>>>(z, el, er, offs, ssrc, gat_bias, h, h8);

  // link scores (pos+neg fused, fp8 gathers) + loss
  score_kernel<<<2048, 256, 0, stream>>>(h8, pos_src, pos_dst, neg_src, neg_dst, l_pos, l_neg,
                                         maxacc, P);
  loss_sum_kernel<<<1024, 256, 0, stream>>>(l_pos, l_neg, maxacc, alpha, sums, P);
  final_kernel<<<1, 1, 0, stream>>>(sums, out_loss);

  // prediction head: out = h[:NUSER] @ W_pred + b_pred (bf16 MFMA)
  predgemm_kernel<<<(NUSER + 63) / 64, 256, 0, stream>>>(h, Bp_p, b_pred, out_pred, NUSER);

  (void)n_in; (void)out_size; (void)ws_size;
}

// Round 7
// 258.125 us; speedup vs baseline: 3.7679x; 1.1210x over previous
//
#include <hip/hip_runtime.h>
#include <hip/hip_bf16.h>
#include <math.h>

#define NUSER 60000
#define NITEM 60000
#define NNODE 120000
#define BSH 9
#define NB 235           // ceil(NNODE / 512)
#define CAP 8192         // per-bucket LDS capacity (mean ~6.9k, sigma ~83)

typedef __attribute__((ext_vector_type(8))) short bf16x8;
typedef __attribute__((ext_vector_type(4))) float f32x4;
typedef __attribute__((ext_vector_type(2))) float f32x2;
typedef __attribute__((ext_vector_type(4))) unsigned short u16x4;

__device__ __forceinline__ float leaky02(float x) { return x > 0.f ? x : 0.2f * x; }

__device__ __forceinline__ float inv_ord(unsigned int u) {
  unsigned int bits = (u & 0x80000000u) ? (u & 0x7FFFFFFFu) : ~u;
  return __uint_as_float(bits);
}
__device__ __forceinline__ unsigned int ord_of(float f) {
  unsigned int u = __float_as_uint(f);
  return (u & 0x80000000u) ? ~u : (u | 0x80000000u);
}
__device__ __forceinline__ short f2bs(float f) {
  __hip_bfloat16 h = __float2bfloat16(f);
  return *reinterpret_cast<short*>(&h);
}

// acc += w * unpack2(fp8 pair in low 16 bits of u)
__device__ __forceinline__ void f8fma(f32x2& acc, float w, unsigned int u) {
  f32x2 zz = __builtin_amdgcn_cvt_pk_f32_fp8(u, false);
  f32x2 ww; ww.x = w; ww.y = w;
  acc = __builtin_elementwise_fma(ww, zz, acc);
}
// acc += dot of 4 fp8 pairs (ua, ub are 4 packed e4m3 each)
__device__ __forceinline__ void fp8dot(f32x2& acc, unsigned int ua, unsigned int ub) {
  f32x2 a0 = __builtin_amdgcn_cvt_pk_f32_fp8(ua, false);
  f32x2 a1 = __builtin_amdgcn_cvt_pk_f32_fp8(ua, true);
  f32x2 b0 = __builtin_amdgcn_cvt_pk_f32_fp8(ub, false);
  f32x2 b1 = __builtin_amdgcn_cvt_pk_f32_fp8(ub, true);
  acc = __builtin_elementwise_fma(a0, b0, acc);
  acc = __builtin_elementwise_fma(a1, b1, acc);
}

// ---- prep: fused weight-product + MFMA B-fragment packing, all 3 matrices + biases.
// Bp_u[t] = bf16(sum_j W_user[k][j]*W_gat[j][n])   (K=256, N=128)
// Bp_i[t] = bf16(sum_j W_item[k][j]*W_gat[j][n])   (K=128, N=128)
// Bp_p[t] = bf16(W_pred[k][n])                     (K=128, N=64, pack only)
// bf_u[n] = sum_j b_user[j]*W_gat[j][n]; bf_i likewise.
__global__ __launch_bounds__(256) void prep_kernel(
    const float* __restrict__ Wu, const float* __restrict__ bu, const float* __restrict__ Wi,
    const float* __restrict__ bi, const float* __restrict__ Wg, const float* __restrict__ Wp,
    __hip_bfloat16* __restrict__ Bp_u, __hip_bfloat16* __restrict__ Bp_i,
    __hip_bfloat16* __restrict__ Bp_p, float* __restrict__ bf_u, float* __restrict__ bf_i) {
  int t = blockIdx.x * 256 + threadIdx.x;
  if (t < 32768) {
    int j = t & 7, lane = (t >> 3) & 63, rest = t >> 9;
    int nt = rest & 7, ks = rest >> 3;
    int k = ks * 32 + ((lane >> 4) << 3) + j;
    int n = nt * 16 + (lane & 15);
    float acc = 0.f;
#pragma unroll 8
    for (int jj = 0; jj < 128; ++jj) acc = fmaf(Wu[k * 128 + jj], Wg[jj * 128 + n], acc);
    Bp_u[t] = __float2bfloat16(acc);
  } else if (t < 49152) {
    int tt = t - 32768;
    int j = tt & 7, lane = (tt >> 3) & 63, rest = tt >> 9;
    int nt = rest & 7, ks = rest >> 3;
    int k = ks * 32 + ((lane >> 4) << 3) + j;
    int n = nt * 16 + (lane & 15);
    float acc = 0.f;
#pragma unroll 8
    for (int jj = 0; jj < 128; ++jj) acc = fmaf(Wi[k * 128 + jj], Wg[jj * 128 + n], acc);
    Bp_i[tt] = __float2bfloat16(acc);
  } else if (t < 57344) {
    int tt = t - 49152;
    int j = tt & 7, lane = (tt >> 3) & 63, rest = tt >> 9;
    int nt = rest & 3, ks = rest >> 2;
    int k = ks * 32 + ((lane >> 4) << 3) + j;
    int n = nt * 16 + (lane & 15);
    Bp_p[tt] = __float2bfloat16(Wp[k * 64 + n]);
  } else if (t < 57344 + 256) {
    int n = t - 57344;
    if (n < 128) {
      float acc = 0.f;
      for (int jj = 0; jj < 128; ++jj) acc = fmaf(bu[jj], Wg[jj * 128 + n], acc);
      bf_u[n] = acc;
    } else {
      int nn = n - 128;
      float acc = 0.f;
      for (int jj = 0; jj < 128; ++jj) acc = fmaf(bi[jj], Wg[jj * 128 + nn], acc);
      bf_i[nn] = acc;
    }
  }
}

// ---- z GEMM body: LDS-staged A (fp32 -> bf16 swizzled), MFMA, epilogue -> fp8 z + el/er.
template <int K>
__device__ __forceinline__ void zgemm_body(
    char* smem, const float* __restrict__ A, const __hip_bfloat16* __restrict__ Bp,
    const float* __restrict__ bias, const float* __restrict__ al, const float* __restrict__ ar,
    unsigned char* __restrict__ z8, float* __restrict__ el, float* __restrict__ er, int M,
    int blk) {
  float(*lds)[140] = (float(*)[140])smem;
  const int lane = threadIdx.x & 63, wv = threadIdx.x >> 6;
  const int t = threadIdx.x;
  const int C4 = K / 4;
  for (int f = t; f < 64 * C4; f += 256) {
    int row = f / C4, c4 = f - row * C4;
    int grow = blk * 64 + row;
    if (grow >= M) grow = M - 1;
    float4 a = *(const float4*)(A + (size_t)grow * K + c4 * 4);
    u16x4 pk;
    pk[0] = (unsigned short)f2bs(a.x);
    pk[1] = (unsigned short)f2bs(a.y);
    pk[2] = (unsigned short)f2bs(a.z);
    pk[3] = (unsigned short)f2bs(a.w);
    unsigned int byte = (unsigned int)row * (K * 2) + (unsigned int)c4 * 8;
    byte ^= (row & 7) << 4;
    *(u16x4*)(smem + byte) = pk;
  }
  __syncthreads();
  const bf16x8* bp = (const bf16x8*)Bp;
  const int frow = wv * 16 + (lane & 15);
  f32x4 acc[8] = {};
#pragma unroll
  for (int ks = 0; ks < K / 32; ++ks) {
    unsigned int byte = (unsigned int)frow * (K * 2) + (unsigned int)(ks * 32 + ((lane >> 4) << 3)) * 2;
    byte ^= (frow & 7) << 4;
    bf16x8 af = *(const bf16x8*)(smem + byte);
#pragma unroll
    for (int nt = 0; nt < 8; ++nt) {
      bf16x8 bfr = bp[(ks * 8 + nt) * 64 + lane];
      acc[nt] = __builtin_amdgcn_mfma_f32_16x16x32_bf16(af, bfr, acc[nt], 0, 0, 0);
    }
  }
  __syncthreads();
#pragma unroll
  for (int nt = 0; nt < 8; ++nt) {
    float b = bias[nt * 16 + (lane & 15)];
#pragma unroll
    for (int r = 0; r < 4; ++r)
      lds[wv * 16 + (lane >> 4) * 4 + r][nt * 16 + (lane & 15)] = acc[nt][r] + b;
  }
  __syncthreads();
  int row = threadIdx.x >> 2;
  int q = threadIdx.x & 3;
  int gm = blk * 64 + row;
  float pl = 0.f, pr = 0.f;
  if (gm < M) {
    const float* lrow = &lds[row][q * 32];
#pragma unroll
    for (int v4 = 0; v4 < 4; ++v4) {
      float f[8];
#pragma unroll
      for (int j = 0; j < 8; ++j) {
        f[j] = lrow[v4 * 8 + j];
        int c = q * 32 + v4 * 8 + j;
        pl = fmaf(f[j], al[c], pl);
        pr = fmaf(f[j], ar[c], pr);
      }
      unsigned int w0 = (unsigned int)__builtin_amdgcn_cvt_pk_fp8_f32(f[0], f[1], 0, false);
      w0 = (unsigned int)__builtin_amdgcn_cvt_pk_fp8_f32(f[2], f[3], (int)w0, true);
      unsigned int w1 = (unsigned int)__builtin_amdgcn_cvt_pk_fp8_f32(f[4], f[5], 0, false);
      w1 = (unsigned int)__builtin_amdgcn_cvt_pk_fp8_f32(f[6], f[7], (int)w1, true);
      uint2 st; st.x = w0; st.y = w1;
      *(uint2*)(z8 + (size_t)gm * 128 + q * 32 + v4 * 8) = st;
    }
  }
  pl += __shfl_xor(pl, 1, 64); pl += __shfl_xor(pl, 2, 64);
  pr += __shfl_xor(pr, 1, 64); pr += __shfl_xor(pr, 2, 64);
  if (q == 0 && gm < M) { el[gm] = pl; er[gm] = pr; }
}

// ---- merged z GEMM: blocks [0,GU) -> user (K=256), [GU,..) -> item (K=128)
__global__ __launch_bounds__(256) void zgemm_kernel(
    const float* __restrict__ Au, const __hip_bfloat16* __restrict__ Bpu,
    const float* __restrict__ bfu, const float* __restrict__ Ai,
    const __hip_bfloat16* __restrict__ Bpi, const float* __restrict__ bfi,
    const float* __restrict__ al, const float* __restrict__ ar, unsigned char* __restrict__ z8,
    float* __restrict__ el, float* __restrict__ er, int GU) {
  __shared__ __align__(16) char smem[64 * 140 * 4];
  if ((int)blockIdx.x < GU)
    zgemm_body<256>(smem, Au, Bpu, bfu, al, ar, z8, el, er, NUSER, blockIdx.x);
  else
    zgemm_body<128>(smem, Ai, Bpi, bfi, al, ar, z8 + (size_t)NUSER * 128, el + NUSER, er + NUSER,
                    NITEM, blockIdx.x - GU);
}

// ---- pred GEMM: out[M][64] (fp32) = h[M][128] (bf16) @ Bp(W_pred packed) + b_pred
__global__ __launch_bounds__(256) void predgemm_kernel(
    const __hip_bfloat16* __restrict__ h, const __hip_bfloat16* __restrict__ Bp,
    const float* __restrict__ bias, float* __restrict__ out, int M) {
  const int lane = threadIdx.x & 63, wv = threadIdx.x >> 6;
  const int m0 = blockIdx.x * 64 + wv * 16;
  int arow = m0 + (lane & 15);
  if (arow >= M) arow = M - 1;
  const bf16x8* a0 = (const bf16x8*)(h + (size_t)arow * 128) + (lane >> 4);
  const bf16x8* bp = (const bf16x8*)Bp;
  f32x4 acc[4] = {};
#pragma unroll
  for (int ks = 0; ks < 4; ++ks) {
    bf16x8 af = a0[ks * 4];
#pragma unroll
    for (int nt = 0; nt < 4; ++nt) {
      bf16x8 bfr = bp[(ks * 4 + nt) * 64 + lane];
      acc[nt] = __builtin_amdgcn_mfma_f32_16x16x32_bf16(af, bfr, acc[nt], 0, 0, 0);
    }
  }
#pragma unroll
  for (int nt = 0; nt < 4; ++nt) {
    int col = nt * 16 + (lane & 15);
    float b = bias[col];
#pragma unroll
    for (int r = 0; r < 4; ++r) {
      int m = m0 + (lane >> 4) * 4 + r;
      if (m < M) out[(size_t)m * 64 + col] = acc[nt][r] + b;
    }
  }
}

// ---- CSR build, stage 0: bucket counts
__global__ __launch_bounds__(256) void bcount_kernel(const int* __restrict__ dst,
                                                     int* __restrict__ btotal, int E) {
  __shared__ int cnt[NB];
  for (int t = threadIdx.x; t < NB; t += 256) cnt[t] = 0;
  __syncthreads();
  for (int i = blockIdx.x * 256 + threadIdx.x; i < E; i += gridDim.x * 256)
    atomicAdd(&cnt[dst[i] >> BSH], 1);
  __syncthreads();
  for (int t = threadIdx.x; t < NB; t += 256)
    if (cnt[t]) atomicAdd(&btotal[t], cnt[t]);
}

// ---- stage 1: scan bucket totals -> bucket_start[NB+1], init gcur
__global__ void bscan_kernel(const int* __restrict__ btotal, int* __restrict__ bstart,
                             int* __restrict__ gcur) {
  __shared__ int s[256];
  int t = threadIdx.x;
  int v = (t < NB) ? btotal[t] : 0;
  s[t] = v;
  __syncthreads();
  for (int off = 1; off < 256; off <<= 1) {
    int a = (t >= off) ? s[t - off] : 0;
    __syncthreads();
    s[t] += a;
    __syncthreads();
  }
  int excl = s[t] - v;
  if (t < NB) { bstart[t] = excl; gcur[t] = excl; }
  if (t == NB - 1) bstart[NB] = s[t];
}

// ---- stage 2: scatter packed {src | dst_local<<17} into bucket-grouped scratch
__global__ __launch_bounds__(256) void bscatter_kernel(const int* __restrict__ src,
                                                       const int* __restrict__ dst,
                                                       int* __restrict__ gcur,
                                                       unsigned int* __restrict__ scratch, int E) {
  __shared__ int cnt[NB];
  __shared__ int base[NB];
  for (int t = threadIdx.x; t < NB; t += 256) cnt[t] = 0;
  __syncthreads();
  const int i0 = blockIdx.x * 4096;
  unsigned int v_[16];
  int b_[16], r_[16];
#pragma unroll
  for (int j = 0; j < 16; ++j) {
    int i = i0 + j * 256 + threadIdx.x;
    b_[j] = -1;
    if (i < E) {
      int d = dst[i];
      int s = src[i];
      int b = d >> BSH;
      b_[j] = b;
      r_[j] = atomicAdd(&cnt[b], 1);
      v_[j] = (unsigned int)s | ((unsigned int)(d & 511) << 17);
    }
  }
  __syncthreads();
  for (int t = threadIdx.x; t < NB; t += 256)
    base[t] = cnt[t] ? atomicAdd(&gcur[t], cnt[t]) : 0;
  __syncthreads();
#pragma unroll
  for (int j = 0; j < 16; ++j)
    if (b_[j] >= 0) scratch[base[b_[j]] + r_[j]] = v_[j];
}

// ---- stage 3: per-bucket LDS counting sort -> ssrc (dst-sorted) + offs
__global__ __launch_bounds__(512) void bsort_kernel(const unsigned int* __restrict__ scratch,
                                                    const int* __restrict__ bstart,
                                                    int* __restrict__ offs, int* __restrict__ ssrc) {
  __shared__ unsigned int buf[CAP];
  __shared__ int cnt[512], scn[512], cur[512];
  int b = blockIdx.x, t = threadIdx.x;
  int s = bstart[b], e = bstart[b + 1], n = e - s;
  int d0 = b << BSH;
  int ndst = NNODE - d0;
  if (ndst > 512) ndst = 512;
  cnt[t] = 0;
  cur[t] = 0;
  __syncthreads();
  bool fit = (n <= CAP);
  if (fit) {
    for (int i = t; i < n; i += 512) {
      unsigned int v = scratch[s + i];
      buf[i] = v;
      atomicAdd(&cnt[v >> 17], 1);
    }
  } else {
    for (int i = t; i < n; i += 512) atomicAdd(&cnt[scratch[s + i] >> 17], 1);
  }
  __syncthreads();
  scn[t] = cnt[t];
  __syncthreads();
  for (int off = 1; off < 512; off <<= 1) {
    int a = (t >= off) ? scn[t - off] : 0;
    __syncthreads();
    scn[t] += a;
    __syncthreads();
  }
  int start = scn[t] - cnt[t];
  if (t < ndst) offs[d0 + t] = s + start;
  if (b == NB - 1 && t == 0) offs[NNODE] = e;
  __syncthreads();
  cnt[t] = start;
  __syncthreads();
  if (fit) {
    for (int i = t; i < n; i += 512) {
      unsigned int v = buf[i];
      int dl = v >> 17;
      int r = atomicAdd(&cur[dl], 1);
      ssrc[s + cnt[dl] + r] = (int)(v & 0x1FFFFu);
    }
  } else {
    for (int i = t; i < n; i += 512) {
      unsigned int v = scratch[s + i];
      int dl = v >> 17;
      int r = atomicAdd(&cur[dl], 1);
      ssrc[s + cnt[dl] + r] = (int)(v & 0x1FFFFu);
    }
  }
}

// ---- GAT aggregation: one wave per dst; fp8 z gathers, 8-deep pipeline, pk-fma.
// Writes h (bf16, for predgemm) and h8 (fp8 e4m3, for score gathers).
__global__ __launch_bounds__(256) void aggregate_kernel(
    const unsigned char* __restrict__ z8, const float* __restrict__ el,
    const float* __restrict__ er, const int* __restrict__ offs, const int* __restrict__ ssrc,
    const float* __restrict__ gat_bias, __hip_bfloat16* __restrict__ h,
    unsigned char* __restrict__ h8) {
  __shared__ __align__(16) float2 ew[4][128];
  int wv = threadIdx.x >> 6, lane = threadIdx.x & 63;
  int d = blockIdx.x * 4 + wv;
  int s0 = offs[d], s1 = offs[d + 1];
  int deg = s1 - s0;
  float erd = er[d];
  const unsigned short* zw = (const unsigned short*)z8;  // row = 64 ushorts (128 fp8)
  f32x2 acc = {0.f, 0.f};
  float ssum = 0.f;
  if (deg <= 128) {
    float w0 = 0.f, w1 = 0.f;
    int o0 = 0, o1 = 0;
    if (lane < deg) { int s = ssrc[s0 + lane]; o0 = s << 6; w0 = __expf(leaky02(el[s] + erd)); }
    if (64 + lane < deg) { int s = ssrc[s0 + 64 + lane]; o1 = s << 6; w1 = __expf(leaky02(el[s] + erd)); }
    ew[wv][lane] = make_float2(w0, __int_as_float(o0));
    ew[wv][64 + lane] = make_float2(w1, __int_as_float(o1));
    __builtin_amdgcn_wave_barrier();
    int i = 0;
    for (; i + 8 <= deg; i += 8) {
      float4 p0 = *(const float4*)&ew[wv][i];
      float4 p1 = *(const float4*)&ew[wv][i + 2];
      float4 p2 = *(const float4*)&ew[wv][i + 4];
      float4 p3 = *(const float4*)&ew[wv][i + 6];
      unsigned int u0 = zw[__float_as_uint(p0.y) + lane];
      unsigned int u1 = zw[__float_as_uint(p0.w) + lane];
      unsigned int u2 = zw[__float_as_uint(p1.y) + lane];
      unsigned int u3 = zw[__float_as_uint(p1.w) + lane];
      unsigned int u4 = zw[__float_as_uint(p2.y) + lane];
      unsigned int u5 = zw[__float_as_uint(p2.w) + lane];
      unsigned int u6 = zw[__float_as_uint(p3.y) + lane];
      unsigned int u7 = zw[__float_as_uint(p3.w) + lane];
      ssum += ((p0.x + p0.z) + (p1.x + p1.z)) + ((p2.x + p2.z) + (p3.x + p3.z));
      f8fma(acc, p0.x, u0); f8fma(acc, p0.z, u1);
      f8fma(acc, p1.x, u2); f8fma(acc, p1.z, u3);
      f8fma(acc, p2.x, u4); f8fma(acc, p2.z, u5);
      f8fma(acc, p3.x, u6); f8fma(acc, p3.z, u7);
    }
    for (; i + 2 <= deg; i += 2) {
      float4 p = *(const float4*)&ew[wv][i];
      unsigned int ua = zw[__float_as_uint(p.y) + lane];
      unsigned int ub = zw[__float_as_uint(p.w) + lane];
      ssum += p.x + p.z;
      f8fma(acc, p.x, ua); f8fma(acc, p.z, ub);
    }
    if (i < deg) {
      float2 pp = ew[wv][i];
      unsigned int u = zw[__float_as_uint(pp.y) + lane];
      ssum += pp.x;
      f8fma(acc, pp.x, u);
    }
  } else {
    for (int i2 = s0; i2 < s1; ++i2) {
      int s = ssrc[i2];
      float w = __expf(leaky02(el[s] + erd));
      ssum += w;
      unsigned int u = zw[((unsigned int)s << 6) + lane];
      f8fma(acc, w, u);
    }
  }
  float inv = 1.f / ssum;
  float o0f = acc.x * inv + gat_bias[lane * 2];
  float o1f = acc.y * inv + gat_bias[lane * 2 + 1];
  o0f = (o0f > 0.f) ? o0f : (__expf(o0f) - 1.f);
  o1f = (o1f > 0.f) ? o1f : (__expf(o1f) - 1.f);
  ushort2 ov;
  ov.x = (unsigned short)((unsigned int)f2bs(o0f) & 0xFFFFu);
  ov.y = (unsigned short)((unsigned int)f2bs(o1f) & 0xFFFFu);
  *(ushort2*)((unsigned short*)h + (size_t)d * 128 + lane * 2) = ov;
  int pk8 = __builtin_amdgcn_cvt_pk_fp8_f32(o0f, o1f, 0, false);
  *(unsigned short*)(h8 + (size_t)d * 128 + lane * 2) = (unsigned short)(pk8 & 0xFFFF);
}

// ---- link scores from fp8 h-copy: 16-lane groups, 3-stage pipeline, pos+neg fused.
__global__ __launch_bounds__(256) void score_kernel(
    const unsigned char* __restrict__ h8, const int* __restrict__ ps, const int* __restrict__ pd,
    const int* __restrict__ ns, const int* __restrict__ nd, float* __restrict__ l_pos,
    float* __restrict__ l_neg, unsigned int* __restrict__ maxacc, int P) {
  const int g16 = threadIdx.x >> 4, l16 = threadIdx.x & 15;
  const uint2* h2 = (const uint2*)h8;  // 16 uint2 per 128B row
  const int stride = gridDim.x * 16;
  const int tot = 2 * P;
  float mpos = -1e30f, mneg = -1e30f;

  int i = blockIdx.x * 16 + g16;
  int aC = 0, bC = 0;
  if (i < tot) {
    bool n = i >= P; int j = n ? i - P : i;
    aC = n ? ns[j] : ps[j]; bC = n ? nd[j] : pd[j];
  }
  uint2 vaC = {0, 0}, vbC = {0, 0};
  if (i < tot) {
    vaC = h2[(size_t)aC * 16 + l16];
    vbC = h2[(size_t)bC * 16 + l16];
  }
  int i1 = i + stride;
  int aN = 0, bN = 0;
  if (i1 < tot) {
    bool n = i1 >= P; int j = n ? i1 - P : i1;
    aN = n ? ns[j] : ps[j]; bN = n ? nd[j] : pd[j];
  }

  while (i < tot) {
    uint2 vaN = {0, 0}, vbN = {0, 0};
    if (i1 < tot) {
      vaN = h2[(size_t)aN * 16 + l16];
      vbN = h2[(size_t)bN * 16 + l16];
    }
    int i2 = i1 + stride;
    int aN2 = 0, bN2 = 0;
    if (i2 < tot) {
      bool n = i2 >= P; int j = n ? i2 - P : i2;
      aN2 = n ? ns[j] : ps[j]; bN2 = n ? nd[j] : pd[j];
    }
    f32x2 acc = {0.f, 0.f};
    fp8dot(acc, vaC.x, vbC.x);
    fp8dot(acc, vaC.y, vbC.y);
    float s = acc.x + acc.y;
    s += __shfl_xor(s, 1, 16);
    s += __shfl_xor(s, 2, 16);
    s += __shfl_xor(s, 4, 16);
    s += __shfl_xor(s, 8, 16);
    float lv = fminf(s, 0.f) - log1pf(__expf(-fabsf(s)));
    bool neg = i >= P;
    int j = neg ? i - P : i;
    if (l16 == 0) (neg ? l_neg : l_pos)[j] = lv;
    if (neg) mneg = fmaxf(mneg, lv); else mpos = fmaxf(mpos, lv);
    i = i1; i1 = i2;
    aC = aN; bC = bN; aN = aN2; bN = bN2;
    vaC = vaN; vbC = vbN;
  }
  __shared__ float red0[256], red1[256];
  red0[threadIdx.x] = mpos;
  red1[threadIdx.x] = mneg;
  __syncthreads();
  for (int off = 128; off; off >>= 1) {
    if (threadIdx.x < off) {
      red0[threadIdx.x] = fmaxf(red0[threadIdx.x], red0[threadIdx.x + off]);
      red1[threadIdx.x] = fmaxf(red1[threadIdx.x], red1[threadIdx.x + off]);
    }
    __syncthreads();
  }
  if (threadIdx.x == 0) {
    atomicMax(maxacc + 0, ord_of(red0[0]));
    atomicMax(maxacc + 1, ord_of(red1[0]));
  }
}

// ---- thresholded sum (both sets, one launch): which = blockIdx>>9
__global__ __launch_bounds__(256) void loss_sum_kernel(const float* __restrict__ l_pos,
                                                       const float* __restrict__ l_neg,
                                                       const unsigned int* __restrict__ maxacc,
                                                       const int* __restrict__ alpha,
                                                       float* __restrict__ sums, int P) {
  __shared__ float sdata[256];
  int which = blockIdx.x >> 9;
  const float* l = which ? l_neg : l_pos;
  float a = (float)alpha[0];
  float kT = (0.5f <= a) ? 0.5f : a;
  float hold = kT * inv_ord(maxacc[which]);
  float s = 0.f;
  for (int i = (blockIdx.x & 511) * 256 + threadIdx.x; i < P; i += 512 * 256) {
    float v = l[i];
    if (!(v > hold)) s += v;
  }
  sdata[threadIdx.x] = s;
  __syncthreads();
  for (int off = 128; off; off >>= 1) {
    if (threadIdx.x < off) sdata[threadIdx.x] += sdata[threadIdx.x + off];
    __syncthreads();
  }
  if (threadIdx.x == 0) atomicAdd(&sums[which], sdata[0]);
}

__global__ void final_kernel(const float* __restrict__ sums, float* __restrict__ out) {
  out[0] = -(sums[0] + sums[1]);
}

extern "C" void kernel_launch(void* const* d_in, const int* in_sizes, int n_in,
                              void* d_out, int out_size, void* d_ws, size_t ws_size,
                              hipStream_t stream) {
  const float* feat_user = (const float*)d_in[0];
  const float* feat_item = (const float*)d_in[1];
  const float* W_user = (const float*)d_in[2];
  const float* b_user = (const float*)d_in[3];
  const float* W_item = (const float*)d_in[4];
  const float* b_item = (const float*)d_in[5];
  const float* W_gat = (const float*)d_in[6];
  const float* attn_l = (const float*)d_in[7];
  const float* attn_r = (const float*)d_in[8];
  const float* gat_bias = (const float*)d_in[9];
  const float* W_pred = (const float*)d_in[10];
  const float* b_pred = (const float*)d_in[11];
  const int* src = (const int*)d_in[12];
  const int* dst = (const int*)d_in[13];
  const int* pos_src = (const int*)d_in[14];
  const int* pos_dst = (const int*)d_in[15];
  const int* neg_src = (const int*)d_in[16];
  const int* neg_dst = (const int*)d_in[17];
  const int* alpha = (const int*)d_in[18];
  const int E = in_sizes[12];
  const int P = in_sizes[14];

  char* p = (char*)d_ws;
  auto alloc = [&](size_t bytes) {
    char* r = p;
    p += (bytes + 255) & ~(size_t)255;
    return r;
  };
  unsigned char* z8 = (unsigned char*)alloc((size_t)NNODE * 128);
  __hip_bfloat16* h = (__hip_bfloat16*)alloc((size_t)NNODE * 128 * 2);
  unsigned char* h8 = (unsigned char*)alloc((size_t)NNODE * 128);
  float* el = (float*)alloc((size_t)NNODE * 4);
  float* er = (float*)alloc((size_t)NNODE * 4);
  __hip_bfloat16* Bp_u = (__hip_bfloat16*)alloc(256 * 128 * 2);
  __hip_bfloat16* Bp_i = (__hip_bfloat16*)alloc(128 * 128 * 2);
  __hip_bfloat16* Bp_p = (__hip_bfloat16*)alloc(128 * 64 * 2);
  float* bf_u = (float*)alloc(128 * 4);
  float* bf_i = (float*)alloc(128 * 4);
  int* offs = (int*)alloc((size_t)(NNODE + 4) * 4);
  int* ssrc = (int*)alloc((size_t)E * 4);
  unsigned int* scratch = (unsigned int*)alloc((size_t)E * 4);
  float* l_pos = (float*)alloc((size_t)P * 4);
  float* l_neg = (float*)alloc((size_t)P * 4);
  int* bstart = (int*)alloc((NB + 1) * 4);
  int* gcur = (int*)alloc(NB * 4);
  // zero region: btotal[NB] | maxacc[2] | sums[2]
  int* btotal = (int*)alloc((NB + 8) * 4);
  unsigned int* maxacc = (unsigned int*)(btotal + NB);
  float* sums = (float*)(maxacc + 2);

  float* out_loss = (float*)d_out;
  float* out_pred = out_loss + 1;

  hipMemsetAsync(btotal, 0, (NB + 8) * 4, stream);

  // fused weight-product + fragment packing (one launch)
  prep_kernel<<<225, 256, 0, stream>>>(W_user, b_user, W_item, b_item, W_gat, W_pred, Bp_u, Bp_i,
                                       Bp_p, bf_u, bf_i);

  // CSR by dst via two-level bucket sort (no global random atomics)
  bcount_kernel<<<512, 256, 0, stream>>>(dst, btotal, E);
  bscan_kernel<<<1, 256, 0, stream>>>(btotal, bstart, gcur);
  bscatter_kernel<<<(E + 4095) / 4096, 256, 0, stream>>>(src, dst, gcur, scratch, E);
  bsort_kernel<<<NB, 512, 0, stream>>>(scratch, bstart, offs, ssrc);

  // z8 = fp8(feat @ Wf + bf), fused el/er epilogue; user+item merged
  const int GU = (NUSER + 63) / 64, GI = (NITEM + 63) / 64;
  zgemm_kernel<<<GU + GI, 256, 0, stream>>>(feat_user, Bp_u, bf_u, feat_item, Bp_i, bf_i, attn_l,
                                            attn_r, z8, el, er, GU);

  // GAT edge-softmax aggregation -> h (bf16) + h8 (fp8)
  aggregate_kernel<<<NNODE / 4, 256, 0, stream>>>(z8, el, er, offs, ssrc, gat_bias, h, h8);

  // link scores (pos+neg fused, fp8 gathers) + loss
  score_kernel<<<2048, 256, 0, stream>>>(h8, pos_src, pos_dst, neg_src, neg_dst, l_pos, l_neg,
                                         maxacc, P);
  loss_sum_kernel<<<1024, 256, 0, stream>>>(l_pos, l_neg, maxacc, alpha, sums, P);
  final_kernel<<<1, 1, 0, stream>>>(sums, out_loss);

  // prediction head: out = h[:NUSER] @ W_pred + b_pred (bf16 MFMA)
  predgemm_kernel<<<(NUSER + 63) / 64, 256, 0, stream>>>(h, Bp_p, b_pred, out_pred, NUSER);

  (void)n_in; (void)out_size; (void)ws_size;
}